// Round 1
// baseline (3348.082 us; speedup 1.0000x reference)
//
#include <hip/hip_runtime.h>
#include <math.h>

#define DEV __device__ __forceinline__

// ---------------- problem dims ----------------
static constexpr int BB   = 128;     // batch
static constexpr int NN   = 300;     // tgt & memory seq len
static constexpr int DM   = 512;     // d_model

typedef __attribute__((ext_vector_type(8))) short short8;   // 8 bf16 = 4 VGPR
typedef __attribute__((ext_vector_type(4))) float f32x4;

// ---------------- helpers ----------------
DEV unsigned short f2bf(float f) {
  unsigned u = __float_as_uint(f);
  unsigned r = (u + 0x7fffu + ((u >> 16) & 1u)) >> 16;
  return (unsigned short)r;
}
DEV unsigned pack_bf16x2(float a, float b) {
  return (unsigned)f2bf(a) | ((unsigned)f2bf(b) << 16);
}
DEV unsigned pack_trunc(float a, float b) {   // truncate-to-bf16 pack (P in [0,1])
  return (__float_as_uint(a) >> 16) | (__float_as_uint(b) & 0xffff0000u);
}

// async global(16B/lane) -> LDS (wave-uniform base + lane*16)
DEV void gld16(const void* g, void* l) {
  __builtin_amdgcn_global_load_lds(
      (const __attribute__((address_space(1))) unsigned int*)g,
      (__attribute__((address_space(3))) unsigned int*)l,
      16, 0, 0);
}

// =================== LayerNorm (one wave per row of 512) -> bf16 out ===================
__global__ __launch_bounds__(256) void ln_kernel(
    const float* __restrict__ X, const float* __restrict__ g,
    const float* __restrict__ b, unsigned short* __restrict__ Y, int rows)
{
  int wv = threadIdx.x >> 6, lane = threadIdx.x & 63;
  int row = blockIdx.x * 4 + wv;
  if (row >= rows) return;
  const float* xp = X + (size_t)row * DM;
  float v[8]; float s = 0.f, s2 = 0.f;
#pragma unroll
  for (int j = 0; j < 8; j++) {
    v[j] = xp[lane + 64 * j]; s += v[j]; s2 += v[j] * v[j];
  }
#pragma unroll
  for (int o = 32; o >= 1; o >>= 1) { s += __shfl_xor(s, o); s2 += __shfl_xor(s2, o); }
  float mean = s * (1.f / 512.f);
  float var  = s2 * (1.f / 512.f) - mean * mean;
  float rstd = rsqrtf(var + 1e-5f);
  unsigned short* yp = Y + (size_t)row * DM;
#pragma unroll
  for (int j = 0; j < 8; j++) {
    int c = lane + 64 * j;
    yp[c] = f2bf((v[j] - mean) * rstd * g[c] + b[c]);
  }
}

// =================== f32 -> bf16 elementwise (weights / memory) ===================
__global__ __launch_bounds__(256) void cvt_bf16(
    const float* __restrict__ in, unsigned short* __restrict__ out, int n4)
{
  int i = blockIdx.x * 256 + threadIdx.x;
  if (i >= n4) return;
  float4 v = ((const float4*)in)[i];
  union { unsigned short s[4]; uint2 u; } o;
  o.s[0] = f2bf(v.x); o.s[1] = f2bf(v.y); o.s[2] = f2bf(v.z); o.s[3] = f2bf(v.w);
  *(uint2*)&out[(size_t)i * 4] = o.u;
}

// =================== transpose f32 [R,C] -> bf16 [Cpad,R], pad rows zero ===================
__global__ __launch_bounds__(256) void transpose_bf16(
    const float* __restrict__ in, unsigned short* __restrict__ out,
    int R, int Ccols, int Cpad)
{
  __shared__ float t[32][33];
  int c0 = blockIdx.x * 32, r0 = blockIdx.y * 32;
  int x = threadIdx.x & 31, y = threadIdx.x >> 5;   // y in 0..7
#pragma unroll
  for (int dy = 0; dy < 32; dy += 8) {
    int r = r0 + y + dy, c = c0 + x;
    t[y + dy][x] = (r < R && c < Ccols) ? in[(size_t)r * Ccols + c] : 0.f;
  }
  __syncthreads();
#pragma unroll
  for (int dy = 0; dy < 32; dy += 8) {
    int c = c0 + y + dy, r = r0 + x;
    if (c < Cpad && r < R) out[(size_t)c * R + r] = f2bf(t[x][y + dy]);
  }
}

// =================== OLD fp32-input GEMM (kept for ds-out K=624 and align gemms) ===================
// C[m,n] = sum_k A[m,k] * W[n,k]; EPI: 1 +bias, 3 +bias+R
template<int EPI>
__global__ __launch_bounds__(256) void gemm_bf16(
    const float* __restrict__ A, int lda,
    const float* __restrict__ W, int ldw,
    const float* __restrict__ bias,
    const float* __restrict__ R, int ldr,
    float* __restrict__ C, int ldc,
    int M, int K, int NC)
{
  __shared__ __align__(16) unsigned short As[128 * 40];
  __shared__ __align__(16) unsigned short Bs[128 * 40];
  const int tid = threadIdx.x;
  const int wave = tid >> 6, lane = tid & 63;
  const int wr = wave >> 1, wc = wave & 1;
  const int quad = lane >> 4, l16 = lane & 15;
  const int n0 = blockIdx.x * 128;
  const int m0 = blockIdx.y * 128;
  const int srow = tid >> 1;          // 0..127
  const int skk  = (tid & 1) * 16;    // 0 or 16

  f32x4 acc[4][4];
#pragma unroll
  for (int i = 0; i < 4; i++)
#pragma unroll
    for (int j = 0; j < 4; j++) acc[i][j] = (f32x4){0.f, 0.f, 0.f, 0.f};

  int ar = m0 + srow; if (ar >= M)  ar = M - 1;
  int br = n0 + srow; if (br >= NC) br = NC - 1;
  const float* apr = A + (size_t)ar * lda;
  const float* bpr = W + (size_t)br * ldw;

  for (int k0 = 0; k0 < K; k0 += 32) {
    float4 a0, a1, a2, a3, b0, b1, b2, b3;
    if (k0 + skk < K) {
      const float* ap = apr + k0 + skk;
      const float* bp = bpr + k0 + skk;
      a0 = *(const float4*)(ap);      a1 = *(const float4*)(ap + 4);
      a2 = *(const float4*)(ap + 8);  a3 = *(const float4*)(ap + 12);
      b0 = *(const float4*)(bp);      b1 = *(const float4*)(bp + 4);
      b2 = *(const float4*)(bp + 8);  b3 = *(const float4*)(bp + 12);
    } else {
      a0 = a1 = a2 = a3 = make_float4(0.f, 0.f, 0.f, 0.f);
      b0 = b1 = b2 = b3 = a0;
    }
    __syncthreads();
    {
      uint4 p0 = make_uint4(pack_bf16x2(a0.x, a0.y), pack_bf16x2(a0.z, a0.w),
                            pack_bf16x2(a1.x, a1.y), pack_bf16x2(a1.z, a1.w));
      uint4 p1 = make_uint4(pack_bf16x2(a2.x, a2.y), pack_bf16x2(a2.z, a2.w),
                            pack_bf16x2(a3.x, a3.y), pack_bf16x2(a3.z, a3.w));
      *(uint4*)&As[srow * 40 + skk]     = p0;
      *(uint4*)&As[srow * 40 + skk + 8] = p1;
      uint4 q0 = make_uint4(pack_bf16x2(b0.x, b0.y), pack_bf16x2(b0.z, b0.w),
                            pack_bf16x2(b1.x, b1.y), pack_bf16x2(b1.z, b1.w));
      uint4 q1 = make_uint4(pack_bf16x2(b2.x, b2.y), pack_bf16x2(b2.z, b2.w),
                            pack_bf16x2(b3.x, b3.y), pack_bf16x2(b3.z, b3.w));
      *(uint4*)&Bs[srow * 40 + skk]     = q0;
      *(uint4*)&Bs[srow * 40 + skk + 8] = q1;
    }
    __syncthreads();
    short8 af[4], bf[4];
#pragma unroll
    for (int i = 0; i < 4; i++)
      af[i] = *(const short8*)&As[(wr * 64 + i * 16 + l16) * 40 + quad * 8];
#pragma unroll
    for (int j = 0; j < 4; j++)
      bf[j] = *(const short8*)&Bs[(wc * 64 + j * 16 + l16) * 40 + quad * 8];
#pragma unroll
    for (int i = 0; i < 4; i++)
#pragma unroll
      for (int j = 0; j < 4; j++)
        acc[i][j] = __builtin_amdgcn_mfma_f32_16x16x32_bf16(af[i], bf[j], acc[i][j], 0, 0, 0);
  }

#pragma unroll
  for (int i = 0; i < 4; i++) {
    int rbase = m0 + wr * 64 + i * 16 + quad * 4;
#pragma unroll
    for (int r = 0; r < 4; r++) {
      int row = rbase + r;
      if (row < M) {
        size_t rowc = (size_t)row * ldc;
#pragma unroll
        for (int j = 0; j < 4; j++) {
          int col = n0 + wc * 64 + j * 16 + l16;
          if (col < NC) {
            float e = acc[i][j][r];
            if (EPI == 1 || EPI == 3) e += bias[col];
            if (EPI == 3) e += R[(size_t)row * ldr + col];
            C[rowc + col] = e;
          }
        }
      }
    }
  }
}

// =================== NEW bf16-input GEMM, m97 structure ===================
// A bf16 [M,K] k-major, W bf16 [Npad,K] k-major (Npad mult of 128, pad rows zero).
// global_load_lds width-16 staging into linear LDS [128][32] per matrix.
// EPI: 0 plain f32, 1 +bias f32, 2 relu(+bias) -> bf16, 4 accumulate f32
template<int EPI>
__global__ __launch_bounds__(256) void gemm_bb(
    const unsigned short* __restrict__ A, int lda,
    const unsigned short* __restrict__ W, int ldw,
    const float* __restrict__ bias,
    void* __restrict__ Cv, int ldc,
    int M, int K, int NC)
{
  __shared__ __align__(16) unsigned short As[128 * 32];
  __shared__ __align__(16) unsigned short Bs[128 * 32];
  const int tid = threadIdx.x;
  const int wave = tid >> 6, lane = tid & 63;
  const int wr = wave >> 1, wc = wave & 1;
  const int quad = lane >> 4, l16 = lane & 15;
  const int n0 = blockIdx.x * 128;
  const int m0 = blockIdx.y * 128;

  // staging: 512 chunks of 16B per matrix tile; chunk cc = issue*256 + tid;
  // row = cc>>2, colchunk = cc&3. LDS dst linear: byte cc*16 (wave-uniform base).
  int ra = m0 + (tid >> 2);
  int ra0 = (ra      >= M) ? M - 1 : ra;
  int ra1 = (ra + 64 >= M) ? M - 1 : ra + 64;
  const unsigned short* a0 = A + (size_t)ra0 * lda + (tid & 3) * 8;
  const unsigned short* a1 = A + (size_t)ra1 * lda + (tid & 3) * 8;
  const unsigned short* b0 = W + (size_t)(n0 + (tid >> 2)) * ldw + (tid & 3) * 8;
  const unsigned short* b1 = b0 + (size_t)64 * ldw;
  unsigned short* dA0 = &As[wave * 512];           // issue0: bytes wave*1024
  unsigned short* dA1 = &As[2048 + wave * 512];    // issue1: +4096B
  unsigned short* dB0 = &Bs[wave * 512];
  unsigned short* dB1 = &Bs[2048 + wave * 512];

  f32x4 acc[4][4];
#pragma unroll
  for (int i = 0; i < 4; i++)
#pragma unroll
    for (int j = 0; j < 4; j++) acc[i][j] = (f32x4){0.f, 0.f, 0.f, 0.f};

  for (int k0 = 0; k0 < K; k0 += 32) {
    gld16(a0 + k0, dA0);
    gld16(a1 + k0, dA1);
    gld16(b0 + k0, dB0);
    gld16(b1 + k0, dB1);
    __syncthreads();                 // drains vmcnt -> LDS tiles complete
    short8 af[4], bq[4];
#pragma unroll
    for (int i = 0; i < 4; i++)
      af[i] = *(const short8*)&As[(wr * 64 + i * 16 + l16) * 32 + quad * 8];
#pragma unroll
    for (int j = 0; j < 4; j++)
      bq[j] = *(const short8*)&Bs[(wc * 64 + j * 16 + l16) * 32 + quad * 8];
#pragma unroll
    for (int i = 0; i < 4; i++)
#pragma unroll
      for (int j = 0; j < 4; j++)
        acc[i][j] = __builtin_amdgcn_mfma_f32_16x16x32_bf16(af[i], bq[j], acc[i][j], 0, 0, 0);
    __syncthreads();                 // all reads done before next overwrite
  }

#pragma unroll
  for (int i = 0; i < 4; i++) {
    int rbase = m0 + wr * 64 + i * 16 + quad * 4;
#pragma unroll
    for (int r = 0; r < 4; r++) {
      int row = rbase + r;
      if (row < M) {
        size_t rowc = (size_t)row * ldc;
#pragma unroll
        for (int j = 0; j < 4; j++) {
          int col = n0 + wc * 64 + j * 16 + l16;
          if (col < NC) {
            float e = acc[i][j][r];
            if (EPI == 1 || EPI == 2) e += bias[col];
            if (EPI == 2) {
              ((unsigned short*)Cv)[rowc + col] = f2bf(fmaxf(e, 0.f));
            } else if (EPI == 4) {
              ((float*)Cv)[rowc + col] += e;
            } else {
              ((float*)Cv)[rowc + col] = e;
            }
          }
        }
      }
    }
  }
}

// =================== ds (kinematic-tree) attention ===================
__global__ __launch_bounds__(256) void ds_attn_kernel(
    const float* __restrict__ COMB, float* __restrict__ V)
{
  __shared__ float ks[4][2][24][6];
  __shared__ float vs[4][2][24][6];
  int wv = threadIdx.x >> 6, lane = threadIdx.x & 63;
  int half = lane >> 5, i = lane & 31;
  int u  = blockIdx.x * 4 + wv;     // head-pair unit
  int bn = u >> 1, hp = u & 1;
  int h  = hp * 2 + half;
  size_t cbase = (size_t)bn * 1248 + h * 156 + 3;
  size_t vbase = (size_t)bn * 624  + h * 156 + 3;

  float q[6];
  if (i < 24) {
#pragma unroll
    for (int j = 0; j < 6; j++) {
      q[j]                 = COMB[cbase + i * 6 + j];
      ks[wv][half][i][j]   = COMB[cbase + 624 + i * 6 + j];
      vs[wv][half][i][j]   = V[vbase + i * 6 + j];
    }
  } else {
#pragma unroll
    for (int j = 0; j < 6; j++) q[j] = 0.f;
  }
  __syncthreads();

  float p[24];
#pragma unroll
  for (int k = 0; k < 24; k++) p[k] = 0.f;

  if (i < 24) {
    float mx = -1e30f;
#pragma unroll
    for (int k = 0; k < 24; k++) {
      float s = 0.f;
#pragma unroll
      for (int j = 0; j < 6; j++) s += q[j] * ks[wv][half][k][j];
      s *= 0.4082482904638631f;   // 1/sqrt(6)
      p[k] = s; mx = fmaxf(mx, s);
    }
    float sum = 0.f;
#pragma unroll
    for (int k = 0; k < 24; k++) { p[k] = __expf(p[k] - mx); sum += p[k]; }
    float inv = 1.f / sum;
#pragma unroll
    for (int k = 0; k < 24; k++) p[k] *= inv;
  }

  {
    float c = p[0];
    float t;
    t = __shfl(c, 3, 32);  if (i == 6) c = (c + t) * 0.5f;
    t = __shfl(c, 6, 32);  if (i == 9) c = (c + t) * 0.5f;
    t = __shfl(c, 9, 32);  if (i >= 12 && i <= 14) c = (c + t) * 0.5f;
    int src = (i >= 3) ? (i - 3) : 0;
    t = __shfl(c, src, 32); if (i >= 15 && i <= 17) c = (c + t) * 0.5f;
    p[0] = c;
  }
  if (i == 0) {
    p[6]  = (p[6]  + p[3])  * 0.5f;
    p[9]  = (p[9]  + p[6])  * 0.5f;
    p[12] = (p[12] + p[9])  * 0.5f;
    p[13] = (p[13] + p[9])  * 0.5f;
    p[14] = (p[14] + p[9])  * 0.5f;
    p[16] = (p[16] + p[13]) * 0.5f;
    p[17] = (p[17] + p[14]) * 0.5f;
    p[15] = (p[15] + p[12]) * 0.5f;
  }

  if (i < 24) {
    float o[6] = {0.f, 0.f, 0.f, 0.f, 0.f, 0.f};
#pragma unroll
    for (int k = 0; k < 24; k++) {
#pragma unroll
      for (int j = 0; j < 6; j++) o[j] += p[k] * vs[wv][half][k][j];
    }
#pragma unroll
    for (int j = 0; j < 6; j++) V[vbase + i * 6 + j] = o[j];
  }
}

// =================== MFMA MHA (self & cross), dh=64, 8 heads ===================
// Output now bf16 (feeds out-proj GEMM A directly; same f2bf rounding as before).
__global__ __launch_bounds__(512) void mha_mfma(
    const float* __restrict__ Qp, int ldq, int qoff,
    const float* __restrict__ KVp, int ldkv, int koff, int voff,
    unsigned short* __restrict__ Op, float scale)
{
  __shared__ __align__(16) unsigned short Ksh[304 * 72];
  __shared__ __align__(16) unsigned short Vt[64 * 328];
  __shared__ __align__(16) unsigned short Pt[8][16 * 40];
  const int bh = blockIdx.x, b = bh >> 3, h = bh & 7;
  const int tid = threadIdx.x, wv = tid >> 6, lane = tid & 63;
  const int quad = lane >> 4, l16 = lane & 15;
  const size_t kbase = (size_t)b * NN * ldkv + koff + h * 64;
  const size_t vbase = (size_t)b * NN * ldkv + voff + h * 64;

  for (int f = tid; f < 304 * 16; f += 512) {
    int rk = f >> 4, c4 = (f & 15) * 4;
    uint2 w;
    if (rk < 300) {
      float4 kx = *(const float4*)(KVp + kbase + (size_t)rk * ldkv + c4);
      w.x = pack_bf16x2(kx.x, kx.y); w.y = pack_bf16x2(kx.z, kx.w);
    } else { w.x = 0u; w.y = 0u; }
    *(uint2*)&Ksh[rk * 72 + c4] = w;
  }
  for (int f = tid; f < 64 * 164; f += 512) {
    int d = f & 63, s0 = (f >> 6) * 2;
    unsigned w = 0u;
    if (s0 < 300) {
      float v0 = KVp[vbase + (size_t)s0 * ldkv + d];
      float v1 = (s0 + 1 < 300) ? KVp[vbase + (size_t)(s0 + 1) * ldkv + d] : 0.f;
      w = pack_bf16x2(v0, v1);
    }
    *(unsigned*)&Vt[d * 328 + s0] = w;
  }
  __syncthreads();

  unsigned short* pt = &Pt[wv][0];

  for (int qt = wv; qt < 19; qt += 8) {
    int qrow = qt * 16 + l16; if (qrow > 299) qrow = 299;
    const float* qp = Qp + (size_t)(b * NN + qrow) * ldq + qoff + h * 64 + quad * 8;
    short8 qf[2];
#pragma unroll
    for (int ks = 0; ks < 2; ks++) {
      float4 x0 = *(const float4*)(qp + ks * 32);
      float4 x1 = *(const float4*)(qp + ks * 32 + 4);
      union { unsigned u[4]; short8 s; } cv;
      cv.u[0] = pack_bf16x2(x0.x, x0.y); cv.u[1] = pack_bf16x2(x0.z, x0.w);
      cv.u[2] = pack_bf16x2(x1.x, x1.y); cv.u[3] = pack_bf16x2(x1.z, x1.w);
      qf[ks] = cv.s;
    }

    f32x4 sacc[19];
#pragma unroll
    for (int t = 0; t < 19; t++) {
      short8 k0 = *(const short8*)&Ksh[(t * 16 + l16) * 72 + quad * 8];
      short8 k1 = *(const short8*)&Ksh[(t * 16 + l16) * 72 + 32 + quad * 8];
      f32x4 a = (f32x4){0.f, 0.f, 0.f, 0.f};
      a = __builtin_amdgcn_mfma_f32_16x16x32_bf16(k0, qf[0], a, 0, 0, 0);
      a = __builtin_amdgcn_mfma_f32_16x16x32_bf16(k1, qf[1], a, 0, 0, 0);
      sacc[t] = a;
    }

    float mx = -1e30f;
#pragma unroll
    for (int t = 0; t < 19; t++)
#pragma unroll
      for (int r = 0; r < 4; r++) mx = fmaxf(mx, sacc[t][r]);
    mx = fmaxf(mx, __shfl_xor(mx, 16));
    mx = fmaxf(mx, __shfl_xor(mx, 32));
    float sum = 0.f;
#pragma unroll
    for (int t = 0; t < 19; t++) {
#pragma unroll
      for (int r = 0; r < 4; r++) {
        float p = __expf((sacc[t][r] - mx) * scale);
        if (t == 18 && quad == 3) p = 0.f;
        sacc[t][r] = p; sum += p;
      }
    }
    sum += __shfl_xor(sum, 16);
    sum += __shfl_xor(sum, 32);
    float inv = 1.f / sum;

    f32x4 oacc[4];
#pragma unroll
    for (int dt = 0; dt < 4; dt++) oacc[dt] = (f32x4){0.f, 0.f, 0.f, 0.f};
#pragma unroll
    for (int c = 0; c < 10; c++) {
#pragma unroll
      for (int tic = 0; tic < 2; tic++) {
        int t = 2 * c + tic;
        unsigned w0 = 0u, w1 = 0u;
        if (t < 19) {
          w0 = pack_trunc(sacc[t][0], sacc[t][1]);
          w1 = pack_trunc(sacc[t][2], sacc[t][3]);
        }
        *(unsigned*)&pt[l16 * 40 + tic * 16 + quad * 4]     = w0;
        *(unsigned*)&pt[l16 * 40 + tic * 16 + quad * 4 + 2] = w1;
      }
      short8 pa = *(const short8*)&pt[l16 * 40 + quad * 8];
#pragma unroll
      for (int dt = 0; dt < 4; dt++) {
        short8 vb = *(const short8*)&Vt[(dt * 16 + l16) * 328 + c * 32 + quad * 8];
        oacc[dt] = __builtin_amdgcn_mfma_f32_16x16x32_bf16(pa, vb, oacc[dt], 0, 0, 0);
      }
    }

#pragma unroll
    for (int r = 0; r < 4; r++) {
      int row = qt * 16 + quad * 4 + r;
      float iv = __shfl(inv, quad * 4 + r);
      if (row < 300) {
        unsigned short* op = Op + (size_t)(b * NN + row) * DM + h * 64 + l16;
#pragma unroll
        for (int dt = 0; dt < 4; dt++)
          op[dt * 16] = f2bf(oacc[dt][r] * iv);
      }
    }
  }
}

// =================== column mean over seq + mish(t + mean) ===================
__global__ __launch_bounds__(256) void colmean_mish(
    const float* __restrict__ Y, const float* __restrict__ tvec,
    float* __restrict__ mm)
{
  int g = blockIdx.x * 256 + threadIdx.x;
  int b = g >> 9, d = g & 511;
  const float* yp = Y + (size_t)b * NN * DM + d;
  float s = 0.f;
  for (int n = 0; n < NN; n++) s += yp[(size_t)n * DM];
  float v = tvec[g] + s * (1.f / 300.f);
  float sp = (v > 20.f) ? v : log1pf(__expf(v));
  mm[g] = v * tanhf(sp);
}

// =================== X += (Hw+1)*Y + Hb ===================
__global__ __launch_bounds__(256) void align_apply(
    float* __restrict__ X, const float* __restrict__ Y,
    const float* __restrict__ H)
{
  int idx = blockIdx.x * 256 + threadIdx.x;  // rows*128 float4s
  int row = idx >> 7;
  int d4  = (idx & 127) * 4;
  int b   = row / NN;
  float4 y = *(const float4*)&Y[(size_t)row * DM + d4];
  float4 x = *(const float4*)&X[(size_t)row * DM + d4];
  const float* hw = H + (size_t)b * 1024 + d4;
  const float* hb = hw + 512;
  x.x += (hw[0] + 1.f) * y.x + hb[0];
  x.y += (hw[1] + 1.f) * y.y + hb[1];
  x.z += (hw[2] + 1.f) * y.z + hb[2];
  x.w += (hw[3] + 1.f) * y.w + hb[3];
  *(float4*)&X[(size_t)row * DM + d4] = x;
}

// =================== launch ===================
extern "C" void kernel_launch(void* const* d_in, const int* in_sizes, int n_in,
                              void* d_out, int out_size, void* d_ws, size_t ws_size,
                              hipStream_t stream)
{
  const float* tgt      = (const float*)d_in[0];
  const float* memory   = (const float*)d_in[1];
  const float* tvec     = (const float*)d_in[2];
  const float* qk_w     = (const float*)d_in[3];
  const float* v_w      = (const float*)d_in[4];
  const float* ds_lw    = (const float*)d_in[5];
  const float* ds_lb    = (const float*)d_in[6];
  const float* ta_in_w  = (const float*)d_in[7];
  const float* ta_in_b  = (const float*)d_in[8];
  const float* ta_out_w = (const float*)d_in[9];
  const float* ta_out_b = (const float*)d_in[10];
  const float* ca_in_w  = (const float*)d_in[11];
  const float* ca_in_b  = (const float*)d_in[12];
  const float* ca_out_w = (const float*)d_in[13];
  const float* ca_out_b = (const float*)d_in[14];
  const float* l1_w     = (const float*)d_in[15];
  const float* l1_b     = (const float*)d_in[16];
  const float* l2_w     = (const float*)d_in[17];
  const float* l2_b     = (const float*)d_in[18];
  const float* n1_g = (const float*)d_in[19]; const float* n1_b = (const float*)d_in[20];
  const float* n2_g = (const float*)d_in[21]; const float* n2_b = (const float*)d_in[22];
  const float* n3_g = (const float*)d_in[23]; const float* n3_b = (const float*)d_in[24];
  const float* n4_g = (const float*)d_in[25]; const float* n4_b = (const float*)d_in[26];
  const float* a1_w = (const float*)d_in[27]; const float* a1_b = (const float*)d_in[28];
  const float* a2_w = (const float*)d_in[29]; const float* a2_b = (const float*)d_in[30];
  const float* a3_w = (const float*)d_in[31]; const float* a3_b = (const float*)d_in[32];

  // ---- workspace layout (bytes) ----
  const size_t W_QKT = 1280ULL * 512 * 2;
  const size_t W_VT  = 640ULL  * 512 * 2;
  const size_t W_TAI = 1536ULL * 512 * 2;
  const size_t W_TAO = 512ULL  * 512 * 2;
  const size_t W_CAI = 1536ULL * 512 * 2;
  const size_t W_CAO = 512ULL  * 512 * 2;
  const size_t W_L1  = 2048ULL * 512 * 2;
  const size_t W_L2  = 512ULL  * 2048 * 2;
  const size_t W_MEM = (size_t)BB * NN * 512 * 2;
  const size_t fixedB = W_QKT + W_VT + W_TAI + W_TAO + W_CAI + W_CAO + W_L1 + W_L2 + W_MEM;
  // per-batch: XNh bf16 + T2h bf16 + T1 f32(1536) + T2 f32(1024) + Yb f32 + MM + Hb
  const size_t per_b = 300ULL*512*2 + 300ULL*1024*2 + 300ULL*1536*4 + 300ULL*1024*4
                     + 300ULL*512*4 + 512ULL*4 + 1024ULL*4;   // 4,614,144
  int Bc = 128;
  while (Bc > 16 && fixedB + (size_t)Bc * per_b > ws_size) Bc >>= 1;
  const int rows = Bc * NN;
  const int mB   = (rows + 127) / 128;
  const int aB   = (Bc + 127) / 128;
  const int nchunks = BB / Bc;

  char* p = (char*)d_ws;
  unsigned short* qkTh  = (unsigned short*)p; p += W_QKT;
  unsigned short* vTh   = (unsigned short*)p; p += W_VT;
  unsigned short* taiWh = (unsigned short*)p; p += W_TAI;
  unsigned short* taoWh = (unsigned short*)p; p += W_TAO;
  unsigned short* caiWh = (unsigned short*)p; p += W_CAI;
  unsigned short* caoWh = (unsigned short*)p; p += W_CAO;
  unsigned short* l1Wh  = (unsigned short*)p; p += W_L1;
  unsigned short* l2Wh  = (unsigned short*)p; p += W_L2;
  unsigned short* memh  = (unsigned short*)p; p += W_MEM;
  unsigned short* XNh   = (unsigned short*)p; p += (size_t)rows * 512 * 2;
  unsigned short* T2h   = (unsigned short*)p; p += (size_t)rows * 1024 * 2;
  float* T1 = (float*)p; p += (size_t)rows * 1536 * 4;
  float* T2 = (float*)p; p += (size_t)rows * 1024 * 4;
  float* Yb = (float*)p; p += (size_t)rows * 512 * 4;
  float* MM = (float*)p; p += (size_t)Bc * 512 * 4;
  float* Hb = (float*)p;

  dim3 thr(256);

  // ---- one-time weight / memory conversion ----
  transpose_bf16<<<dim3(40, 16), thr, 0, stream>>>(qk_w, qkTh, 512, 1248, 1280);
  transpose_bf16<<<dim3(20, 16), thr, 0, stream>>>(v_w,  vTh,  512, 624, 640);
  auto cvt = [&](const float* src, unsigned short* dst, size_t n) {
    int n4 = (int)(n / 4);
    cvt_bf16<<<dim3((n4 + 255) / 256), thr, 0, stream>>>(src, dst, n4);
  };
  cvt(ta_in_w,  taiWh, 1536ULL * 512);
  cvt(ta_out_w, taoWh, 512ULL * 512);
  cvt(ca_in_w,  caiWh, 1536ULL * 512);
  cvt(ca_out_w, caoWh, 512ULL * 512);
  cvt(l1_w,     l1Wh,  2048ULL * 512);
  cvt(l2_w,     l2Wh,  512ULL * 2048);
  cvt(memory,   memh,  (size_t)BB * NN * 512);

  for (int c = 0; c < nchunks; ++c) {
    const size_t roff = (size_t)c * Bc * NN * DM;
    const float* tgtC = tgt    + roff;
    const float* tC   = tvec   + (size_t)c * Bc * 512;
    const unsigned short* memhC = memh + roff;
    float*       XC   = (float*)d_out + roff;

    // ---- ds-attention branch: x = tgt + ds_attn(LN1(tgt)) ----
    ln_kernel<<<rows / 4, thr, 0, stream>>>(tgtC, n1_g, n1_b, XNh, rows);
    gemm_bb<0><<<dim3(10, mB), thr, 0, stream>>>(XNh, 512, qkTh, 512, nullptr, T1, 1248, rows, 512, 1248);
    gemm_bb<0><<<dim3(5, mB),  thr, 0, stream>>>(XNh, 512, vTh,  512, nullptr, T2, 624,  rows, 512, 624);
    ds_attn_kernel<<<rows / 2, thr, 0, stream>>>(T1, T2);
    gemm_bf16<3><<<dim3(4, mB), thr, 0, stream>>>(T2, 624, ds_lw, 624, ds_lb, tgtC, 512, XC, 512, rows, 624, 512);

    // ---- self attention + align1 ----
    ln_kernel<<<rows / 4, thr, 0, stream>>>(XC, n2_g, n2_b, XNh, rows);
    gemm_bb<1><<<dim3(12, mB), thr, 0, stream>>>(XNh, 512, taiWh, 512, ta_in_b, T1, 1536, rows, 512, 1536);
    mha_mfma<<<Bc * 8, 512, 0, stream>>>(T1, 1536, 0, T1, 1536, 512, 1024, XNh, 0.125f);
    gemm_bb<1><<<dim3(4, mB),  thr, 0, stream>>>(XNh, 512, taoWh, 512, ta_out_b, Yb, 512, rows, 512, 512);
    colmean_mish<<<Bc * 2, thr, 0, stream>>>(Yb, tC, MM);
    gemm_bf16<1><<<dim3(8, aB), thr, 0, stream>>>(MM, 512, a1_w, 512, a1_b, nullptr, 0, Hb, 1024, Bc, 512, 1024);
    align_apply<<<rows / 2, thr, 0, stream>>>(XC, Yb, Hb);

    // ---- cross attention + align2 ----
    ln_kernel<<<rows / 4, thr, 0, stream>>>(XC, n3_g, n3_b, XNh, rows);
    gemm_bb<1><<<dim3(4, mB),  thr, 0, stream>>>(XNh, 512, caiWh, 512, ca_in_b, T1, 512, rows, 512, 512);
    gemm_bb<1><<<dim3(8, mB),  thr, 0, stream>>>(memhC, 512, caiWh + 512 * 512, 512, ca_in_b + 512, T2, 1024, rows, 512, 1024);
    mha_mfma<<<Bc * 8, 512, 0, stream>>>(T1, 512, 0, T2, 1024, 0, 512, XNh, 0.125f);
    gemm_bb<1><<<dim3(4, mB),  thr, 0, stream>>>(XNh, 512, caoWh, 512, ca_out_b, Yb, 512, rows, 512, 512);
    colmean_mish<<<Bc * 2, thr, 0, stream>>>(Yb, tC, MM);
    gemm_bf16<1><<<dim3(8, aB), thr, 0, stream>>>(MM, 512, a2_w, 512, a2_b, nullptr, 0, Hb, 1024, Bc, 512, 1024);
    align_apply<<<rows / 2, thr, 0, stream>>>(XC, Yb, Hb);

    // ---- FFN (2x1024 halves) + align3 ----
    ln_kernel<<<rows / 4, thr, 0, stream>>>(XC, n4_g, n4_b, XNh, rows);
    gemm_bb<2><<<dim3(8, mB),  thr, 0, stream>>>(XNh, 512, l1Wh, 512, l1_b, T2h, 1024, rows, 512, 1024);
    gemm_bb<1><<<dim3(4, mB),  thr, 0, stream>>>(T2h, 1024, l2Wh, 2048, l2_b, Yb, 512, rows, 1024, 512);
    gemm_bb<2><<<dim3(8, mB),  thr, 0, stream>>>(XNh, 512, l1Wh + 1024 * 512, 512, l1_b + 1024, T2h, 1024, rows, 512, 1024);
    gemm_bb<4><<<dim3(4, mB),  thr, 0, stream>>>(T2h, 1024, l2Wh + 1024, 2048, nullptr, Yb, 512, rows, 1024, 512);
    colmean_mish<<<Bc * 2, thr, 0, stream>>>(Yb, tC, MM);
    gemm_bf16<1><<<dim3(8, aB), thr, 0, stream>>>(MM, 512, a3_w, 512, a3_b, nullptr, 0, Hb, 1024, Bc, 512, 1024);
    align_apply<<<rows / 2, thr, 0, stream>>>(XC, Yb, Hb);
  }
}

// Round 2
// 2677.780 us; speedup vs baseline: 1.2503x; 1.2503x over previous
//
#include <hip/hip_runtime.h>
#include <math.h>

#define DEV __device__ __forceinline__

// ---------------- problem dims ----------------
static constexpr int BB   = 128;     // batch
static constexpr int NN   = 300;     // tgt & memory seq len
static constexpr int DM   = 512;     // d_model

typedef __attribute__((ext_vector_type(8))) short short8;   // 8 bf16 = 4 VGPR
typedef __attribute__((ext_vector_type(4))) float f32x4;

// ---------------- helpers ----------------
DEV unsigned short f2bf(float f) {
  unsigned u = __float_as_uint(f);
  unsigned r = (u + 0x7fffu + ((u >> 16) & 1u)) >> 16;
  return (unsigned short)r;
}
DEV unsigned pack_bf16x2(float a, float b) {
  return (unsigned)f2bf(a) | ((unsigned)f2bf(b) << 16);
}
DEV unsigned pack_trunc(float a, float b) {   // truncate-to-bf16 pack (P in [0,1])
  return (__float_as_uint(a) >> 16) | (__float_as_uint(b) & 0xffff0000u);
}

// async global(16B/lane) -> LDS (wave-uniform base + lane*16)
DEV void gld16(const void* g, void* l) {
  __builtin_amdgcn_global_load_lds(
      (const __attribute__((address_space(1))) unsigned int*)g,
      (__attribute__((address_space(3))) unsigned int*)l,
      16, 0, 0);
}

// =================== LayerNorm (one wave per row of 512) -> bf16 out ===================
__global__ __launch_bounds__(256) void ln_kernel(
    const float* __restrict__ X, const float* __restrict__ g,
    const float* __restrict__ b, unsigned short* __restrict__ Y, int rows)
{
  int wv = threadIdx.x >> 6, lane = threadIdx.x & 63;
  int row = blockIdx.x * 4 + wv;
  if (row >= rows) return;
  const float* xp = X + (size_t)row * DM;
  float v[8]; float s = 0.f, s2 = 0.f;
#pragma unroll
  for (int j = 0; j < 8; j++) {
    v[j] = xp[lane + 64 * j]; s += v[j]; s2 += v[j] * v[j];
  }
#pragma unroll
  for (int o = 32; o >= 1; o >>= 1) { s += __shfl_xor(s, o); s2 += __shfl_xor(s2, o); }
  float mean = s * (1.f / 512.f);
  float var  = s2 * (1.f / 512.f) - mean * mean;
  float rstd = rsqrtf(var + 1e-5f);
  unsigned short* yp = Y + (size_t)row * DM;
#pragma unroll
  for (int j = 0; j < 8; j++) {
    int c = lane + 64 * j;
    yp[c] = f2bf((v[j] - mean) * rstd * g[c] + b[c]);
  }
}

// =================== f32 -> bf16 elementwise (weights / memory) ===================
__global__ __launch_bounds__(256) void cvt_bf16(
    const float* __restrict__ in, unsigned short* __restrict__ out, int n4)
{
  int i = blockIdx.x * 256 + threadIdx.x;
  if (i >= n4) return;
  float4 v = ((const float4*)in)[i];
  union { unsigned short s[4]; uint2 u; } o;
  o.s[0] = f2bf(v.x); o.s[1] = f2bf(v.y); o.s[2] = f2bf(v.z); o.s[3] = f2bf(v.w);
  *(uint2*)&out[(size_t)i * 4] = o.u;
}

// =================== transpose f32 [R,C] -> bf16 [Cpad,R], pad rows zero ===================
__global__ __launch_bounds__(256) void transpose_bf16(
    const float* __restrict__ in, unsigned short* __restrict__ out,
    int R, int Ccols, int Cpad)
{
  __shared__ float t[32][33];
  int c0 = blockIdx.x * 32, r0 = blockIdx.y * 32;
  int x = threadIdx.x & 31, y = threadIdx.x >> 5;   // y in 0..7
#pragma unroll
  for (int dy = 0; dy < 32; dy += 8) {
    int r = r0 + y + dy, c = c0 + x;
    t[y + dy][x] = (r < R && c < Ccols) ? in[(size_t)r * Ccols + c] : 0.f;
  }
  __syncthreads();
#pragma unroll
  for (int dy = 0; dy < 32; dy += 8) {
    int c = c0 + y + dy, r = r0 + x;
    if (c < Cpad && r < R) out[(size_t)c * R + r] = f2bf(t[x][y + dy]);
  }
}

// =================== OLD fp32-input GEMM (kept for ds-out K=624 and align gemms) ===================
// C[m,n] = sum_k A[m,k] * W[n,k]; EPI: 1 +bias, 3 +bias+R
template<int EPI>
__global__ __launch_bounds__(256) void gemm_bf16(
    const float* __restrict__ A, int lda,
    const float* __restrict__ W, int ldw,
    const float* __restrict__ bias,
    const float* __restrict__ R, int ldr,
    float* __restrict__ C, int ldc,
    int M, int K, int NC)
{
  __shared__ __align__(16) unsigned short As[128 * 40];
  __shared__ __align__(16) unsigned short Bs[128 * 40];
  const int tid = threadIdx.x;
  const int wave = tid >> 6, lane = tid & 63;
  const int wr = wave >> 1, wc = wave & 1;
  const int quad = lane >> 4, l16 = lane & 15;
  const int n0 = blockIdx.x * 128;
  const int m0 = blockIdx.y * 128;
  const int srow = tid >> 1;          // 0..127
  const int skk  = (tid & 1) * 16;    // 0 or 16

  f32x4 acc[4][4];
#pragma unroll
  for (int i = 0; i < 4; i++)
#pragma unroll
    for (int j = 0; j < 4; j++) acc[i][j] = (f32x4){0.f, 0.f, 0.f, 0.f};

  int ar = m0 + srow; if (ar >= M)  ar = M - 1;
  int br = n0 + srow; if (br >= NC) br = NC - 1;
  const float* apr = A + (size_t)ar * lda;
  const float* bpr = W + (size_t)br * ldw;

  for (int k0 = 0; k0 < K; k0 += 32) {
    float4 a0, a1, a2, a3, b0, b1, b2, b3;
    if (k0 + skk < K) {
      const float* ap = apr + k0 + skk;
      const float* bp = bpr + k0 + skk;
      a0 = *(const float4*)(ap);      a1 = *(const float4*)(ap + 4);
      a2 = *(const float4*)(ap + 8);  a3 = *(const float4*)(ap + 12);
      b0 = *(const float4*)(bp);      b1 = *(const float4*)(bp + 4);
      b2 = *(const float4*)(bp + 8);  b3 = *(const float4*)(bp + 12);
    } else {
      a0 = a1 = a2 = a3 = make_float4(0.f, 0.f, 0.f, 0.f);
      b0 = b1 = b2 = b3 = a0;
    }
    __syncthreads();
    {
      uint4 p0 = make_uint4(pack_bf16x2(a0.x, a0.y), pack_bf16x2(a0.z, a0.w),
                            pack_bf16x2(a1.x, a1.y), pack_bf16x2(a1.z, a1.w));
      uint4 p1 = make_uint4(pack_bf16x2(a2.x, a2.y), pack_bf16x2(a2.z, a2.w),
                            pack_bf16x2(a3.x, a3.y), pack_bf16x2(a3.z, a3.w));
      *(uint4*)&As[srow * 40 + skk]     = p0;
      *(uint4*)&As[srow * 40 + skk + 8] = p1;
      uint4 q0 = make_uint4(pack_bf16x2(b0.x, b0.y), pack_bf16x2(b0.z, b0.w),
                            pack_bf16x2(b1.x, b1.y), pack_bf16x2(b1.z, b1.w));
      uint4 q1 = make_uint4(pack_bf16x2(b2.x, b2.y), pack_bf16x2(b2.z, b2.w),
                            pack_bf16x2(b3.x, b3.y), pack_bf16x2(b3.z, b3.w));
      *(uint4*)&Bs[srow * 40 + skk]     = q0;
      *(uint4*)&Bs[srow * 40 + skk + 8] = q1;
    }
    __syncthreads();
    short8 af[4], bf[4];
#pragma unroll
    for (int i = 0; i < 4; i++)
      af[i] = *(const short8*)&As[(wr * 64 + i * 16 + l16) * 40 + quad * 8];
#pragma unroll
    for (int j = 0; j < 4; j++)
      bf[j] = *(const short8*)&Bs[(wc * 64 + j * 16 + l16) * 40 + quad * 8];
#pragma unroll
    for (int i = 0; i < 4; i++)
#pragma unroll
      for (int j = 0; j < 4; j++)
        acc[i][j] = __builtin_amdgcn_mfma_f32_16x16x32_bf16(af[i], bf[j], acc[i][j], 0, 0, 0);
  }

#pragma unroll
  for (int i = 0; i < 4; i++) {
    int rbase = m0 + wr * 64 + i * 16 + quad * 4;
#pragma unroll
    for (int r = 0; r < 4; r++) {
      int row = rbase + r;
      if (row < M) {
        size_t rowc = (size_t)row * ldc;
#pragma unroll
        for (int j = 0; j < 4; j++) {
          int col = n0 + wc * 64 + j * 16 + l16;
          if (col < NC) {
            float e = acc[i][j][r];
            if (EPI == 1 || EPI == 3) e += bias[col];
            if (EPI == 3) e += R[(size_t)row * ldr + col];
            C[rowc + col] = e;
          }
        }
      }
    }
  }
}

// =================== bf16-input GEMM, m97 structure ===================
// A bf16 [M,K] k-major, W bf16 [Npad,K] k-major (Npad mult of 128, pad rows zero).
// global_load_lds width-16 staging into linear LDS [128][32] per matrix.
// EPI: 0 plain f32, 1 +bias f32, 2 relu(+bias) -> bf16, 4 accumulate f32
template<int EPI>
__global__ __launch_bounds__(256) void gemm_bb(
    const unsigned short* __restrict__ A, int lda,
    const unsigned short* __restrict__ W, int ldw,
    const float* __restrict__ bias,
    void* __restrict__ Cv, int ldc,
    int M, int K, int NC)
{
  __shared__ __align__(16) unsigned short As[128 * 32];
  __shared__ __align__(16) unsigned short Bs[128 * 32];
  const int tid = threadIdx.x;
  const int wave = tid >> 6, lane = tid & 63;
  const int wr = wave >> 1, wc = wave & 1;
  const int quad = lane >> 4, l16 = lane & 15;
  const int n0 = blockIdx.x * 128;
  const int m0 = blockIdx.y * 128;

  int ra = m0 + (tid >> 2);
  int ra0 = (ra      >= M) ? M - 1 : ra;
  int ra1 = (ra + 64 >= M) ? M - 1 : ra + 64;
  const unsigned short* a0 = A + (size_t)ra0 * lda + (tid & 3) * 8;
  const unsigned short* a1 = A + (size_t)ra1 * lda + (tid & 3) * 8;
  const unsigned short* b0 = W + (size_t)(n0 + (tid >> 2)) * ldw + (tid & 3) * 8;
  const unsigned short* b1 = b0 + (size_t)64 * ldw;
  unsigned short* dA0 = &As[wave * 512];           // issue0: bytes wave*1024
  unsigned short* dA1 = &As[2048 + wave * 512];    // issue1: +4096B
  unsigned short* dB0 = &Bs[wave * 512];
  unsigned short* dB1 = &Bs[2048 + wave * 512];

  f32x4 acc[4][4];
#pragma unroll
  for (int i = 0; i < 4; i++)
#pragma unroll
    for (int j = 0; j < 4; j++) acc[i][j] = (f32x4){0.f, 0.f, 0.f, 0.f};

  for (int k0 = 0; k0 < K; k0 += 32) {
    gld16(a0 + k0, dA0);
    gld16(a1 + k0, dA1);
    gld16(b0 + k0, dB0);
    gld16(b1 + k0, dB1);
    __syncthreads();                 // drains vmcnt -> LDS tiles complete
    short8 af[4], bq[4];
#pragma unroll
    for (int i = 0; i < 4; i++)
      af[i] = *(const short8*)&As[(wr * 64 + i * 16 + l16) * 32 + quad * 8];
#pragma unroll
    for (int j = 0; j < 4; j++)
      bq[j] = *(const short8*)&Bs[(wc * 64 + j * 16 + l16) * 32 + quad * 8];
#pragma unroll
    for (int i = 0; i < 4; i++)
#pragma unroll
      for (int j = 0; j < 4; j++)
        acc[i][j] = __builtin_amdgcn_mfma_f32_16x16x32_bf16(af[i], bq[j], acc[i][j], 0, 0, 0);
    __syncthreads();                 // all reads done before next overwrite
  }

#pragma unroll
  for (int i = 0; i < 4; i++) {
    int rbase = m0 + wr * 64 + i * 16 + quad * 4;
#pragma unroll
    for (int r = 0; r < 4; r++) {
      int row = rbase + r;
      if (row < M) {
        size_t rowc = (size_t)row * ldc;
#pragma unroll
        for (int j = 0; j < 4; j++) {
          int col = n0 + wc * 64 + j * 16 + l16;
          if (col < NC) {
            float e = acc[i][j][r];
            if (EPI == 1 || EPI == 2) e += bias[col];
            if (EPI == 2) {
              ((unsigned short*)Cv)[rowc + col] = f2bf(fmaxf(e, 0.f));
            } else if (EPI == 4) {
              ((float*)Cv)[rowc + col] += e;
            } else {
              ((float*)Cv)[rowc + col] = e;
            }
          }
        }
      }
    }
  }
}

// =================== ds (kinematic-tree) attention ===================
__global__ __launch_bounds__(256) void ds_attn_kernel(
    const float* __restrict__ COMB, float* __restrict__ V)
{
  __shared__ float ks[4][2][24][6];
  __shared__ float vs[4][2][24][6];
  int wv = threadIdx.x >> 6, lane = threadIdx.x & 63;
  int half = lane >> 5, i = lane & 31;
  int u  = blockIdx.x * 4 + wv;     // head-pair unit
  int bn = u >> 1, hp = u & 1;
  int h  = hp * 2 + half;
  size_t cbase = (size_t)bn * 1248 + h * 156 + 3;
  size_t vbase = (size_t)bn * 624  + h * 156 + 3;

  float q[6];
  if (i < 24) {
#pragma unroll
    for (int j = 0; j < 6; j++) {
      q[j]                 = COMB[cbase + i * 6 + j];
      ks[wv][half][i][j]   = COMB[cbase + 624 + i * 6 + j];
      vs[wv][half][i][j]   = V[vbase + i * 6 + j];
    }
  } else {
#pragma unroll
    for (int j = 0; j < 6; j++) q[j] = 0.f;
  }
  __syncthreads();

  float p[24];
#pragma unroll
  for (int k = 0; k < 24; k++) p[k] = 0.f;

  if (i < 24) {
    float mx = -1e30f;
#pragma unroll
    for (int k = 0; k < 24; k++) {
      float s = 0.f;
#pragma unroll
      for (int j = 0; j < 6; j++) s += q[j] * ks[wv][half][k][j];
      s *= 0.4082482904638631f;   // 1/sqrt(6)
      p[k] = s; mx = fmaxf(mx, s);
    }
    float sum = 0.f;
#pragma unroll
    for (int k = 0; k < 24; k++) { p[k] = __expf(p[k] - mx); sum += p[k]; }
    float inv = 1.f / sum;
#pragma unroll
    for (int k = 0; k < 24; k++) p[k] *= inv;
  }

  {
    float c = p[0];
    float t;
    t = __shfl(c, 3, 32);  if (i == 6) c = (c + t) * 0.5f;
    t = __shfl(c, 6, 32);  if (i == 9) c = (c + t) * 0.5f;
    t = __shfl(c, 9, 32);  if (i >= 12 && i <= 14) c = (c + t) * 0.5f;
    int src = (i >= 3) ? (i - 3) : 0;
    t = __shfl(c, src, 32); if (i >= 15 && i <= 17) c = (c + t) * 0.5f;
    p[0] = c;
  }
  if (i == 0) {
    p[6]  = (p[6]  + p[3])  * 0.5f;
    p[9]  = (p[9]  + p[6])  * 0.5f;
    p[12] = (p[12] + p[9])  * 0.5f;
    p[13] = (p[13] + p[9])  * 0.5f;
    p[14] = (p[14] + p[9])  * 0.5f;
    p[16] = (p[16] + p[13]) * 0.5f;
    p[17] = (p[17] + p[14]) * 0.5f;
    p[15] = (p[15] + p[12]) * 0.5f;
  }

  if (i < 24) {
    float o[6] = {0.f, 0.f, 0.f, 0.f, 0.f, 0.f};
#pragma unroll
    for (int k = 0; k < 24; k++) {
#pragma unroll
      for (int j = 0; j < 6; j++) o[j] += p[k] * vs[wv][half][k][j];
    }
#pragma unroll
    for (int j = 0; j < 6; j++) V[vbase + i * 6 + j] = o[j];
  }
}

// =================== MFMA MHA (self & cross), dh=64, 8 heads ===================
// Output bf16 (feeds out-proj GEMM A directly; same f2bf rounding as before).
__global__ __launch_bounds__(512) void mha_mfma(
    const float* __restrict__ Qp, int ldq, int qoff,
    const float* __restrict__ KVp, int ldkv, int koff, int voff,
    unsigned short* __restrict__ Op, float scale)
{
  __shared__ __align__(16) unsigned short Ksh[304 * 72];
  __shared__ __align__(16) unsigned short Vt[64 * 328];
  __shared__ __align__(16) unsigned short Pt[8][16 * 40];
  const int bh = blockIdx.x, b = bh >> 3, h = bh & 7;
  const int tid = threadIdx.x, wv = tid >> 6, lane = tid & 63;
  const int quad = lane >> 4, l16 = lane & 15;
  const size_t kbase = (size_t)b * NN * ldkv + koff + h * 64;
  const size_t vbase = (size_t)b * NN * ldkv + voff + h * 64;

  for (int f = tid; f < 304 * 16; f += 512) {
    int rk = f >> 4, c4 = (f & 15) * 4;
    uint2 w;
    if (rk < 300) {
      float4 kx = *(const float4*)(KVp + kbase + (size_t)rk * ldkv + c4);
      w.x = pack_bf16x2(kx.x, kx.y); w.y = pack_bf16x2(kx.z, kx.w);
    } else { w.x = 0u; w.y = 0u; }
    *(uint2*)&Ksh[rk * 72 + c4] = w;
  }
  for (int f = tid; f < 64 * 164; f += 512) {
    int d = f & 63, s0 = (f >> 6) * 2;
    unsigned w = 0u;
    if (s0 < 300) {
      float v0 = KVp[vbase + (size_t)s0 * ldkv + d];
      float v1 = (s0 + 1 < 300) ? KVp[vbase + (size_t)(s0 + 1) * ldkv + d] : 0.f;
      w = pack_bf16x2(v0, v1);
    }
    *(unsigned*)&Vt[d * 328 + s0] = w;
  }
  __syncthreads();

  unsigned short* pt = &Pt[wv][0];

  for (int qt = wv; qt < 19; qt += 8) {
    int qrow = qt * 16 + l16; if (qrow > 299) qrow = 299;
    const float* qp = Qp + (size_t)(b * NN + qrow) * ldq + qoff + h * 64 + quad * 8;
    short8 qf[2];
#pragma unroll
    for (int ks = 0; ks < 2; ks++) {
      float4 x0 = *(const float4*)(qp + ks * 32);
      float4 x1 = *(const float4*)(qp + ks * 32 + 4);
      union { unsigned u[4]; short8 s; } cv;
      cv.u[0] = pack_bf16x2(x0.x, x0.y); cv.u[1] = pack_bf16x2(x0.z, x0.w);
      cv.u[2] = pack_bf16x2(x1.x, x1.y); cv.u[3] = pack_bf16x2(x1.z, x1.w);
      qf[ks] = cv.s;
    }

    f32x4 sacc[19];
#pragma unroll
    for (int t = 0; t < 19; t++) {
      short8 k0 = *(const short8*)&Ksh[(t * 16 + l16) * 72 + quad * 8];
      short8 k1 = *(const short8*)&Ksh[(t * 16 + l16) * 72 + 32 + quad * 8];
      f32x4 a = (f32x4){0.f, 0.f, 0.f, 0.f};
      a = __builtin_amdgcn_mfma_f32_16x16x32_bf16(k0, qf[0], a, 0, 0, 0);
      a = __builtin_amdgcn_mfma_f32_16x16x32_bf16(k1, qf[1], a, 0, 0, 0);
      sacc[t] = a;
    }

    float mx = -1e30f;
#pragma unroll
    for (int t = 0; t < 19; t++)
#pragma unroll
      for (int r = 0; r < 4; r++) mx = fmaxf(mx, sacc[t][r]);
    mx = fmaxf(mx, __shfl_xor(mx, 16));
    mx = fmaxf(mx, __shfl_xor(mx, 32));
    float sum = 0.f;
#pragma unroll
    for (int t = 0; t < 19; t++) {
#pragma unroll
      for (int r = 0; r < 4; r++) {
        float p = __expf((sacc[t][r] - mx) * scale);
        if (t == 18 && quad == 3) p = 0.f;
        sacc[t][r] = p; sum += p;
      }
    }
    sum += __shfl_xor(sum, 16);
    sum += __shfl_xor(sum, 32);
    float inv = 1.f / sum;

    f32x4 oacc[4];
#pragma unroll
    for (int dt = 0; dt < 4; dt++) oacc[dt] = (f32x4){0.f, 0.f, 0.f, 0.f};
#pragma unroll
    for (int c = 0; c < 10; c++) {
#pragma unroll
      for (int tic = 0; tic < 2; tic++) {
        int t = 2 * c + tic;
        unsigned w0 = 0u, w1 = 0u;
        if (t < 19) {
          w0 = pack_trunc(sacc[t][0], sacc[t][1]);
          w1 = pack_trunc(sacc[t][2], sacc[t][3]);
        }
        *(unsigned*)&pt[l16 * 40 + tic * 16 + quad * 4]     = w0;
        *(unsigned*)&pt[l16 * 40 + tic * 16 + quad * 4 + 2] = w1;
      }
      short8 pa = *(const short8*)&pt[l16 * 40 + quad * 8];
#pragma unroll
      for (int dt = 0; dt < 4; dt++) {
        short8 vb = *(const short8*)&Vt[(dt * 16 + l16) * 328 + c * 32 + quad * 8];
        oacc[dt] = __builtin_amdgcn_mfma_f32_16x16x32_bf16(pa, vb, oacc[dt], 0, 0, 0);
      }
    }

#pragma unroll
    for (int r = 0; r < 4; r++) {
      int row = qt * 16 + quad * 4 + r;
      float iv = __shfl(inv, quad * 4 + r);
      if (row < 300) {
        unsigned short* op = Op + (size_t)(b * NN + row) * DM + h * 64 + l16;
#pragma unroll
        for (int dt = 0; dt < 4; dt++)
          op[dt * 16] = f2bf(oacc[dt][r] * iv);
      }
    }
  }
}

// =================== column mean over seq + mish(t + mean) ===================
__global__ __launch_bounds__(256) void colmean_mish(
    const float* __restrict__ Y, const float* __restrict__ tvec,
    float* __restrict__ mm)
{
  int g = blockIdx.x * 256 + threadIdx.x;
  int b = g >> 9, d = g & 511;
  const float* yp = Y + (size_t)b * NN * DM + d;
  float s = 0.f;
  for (int n = 0; n < NN; n++) s += yp[(size_t)n * DM];
  float v = tvec[g] + s * (1.f / 300.f);
  float sp = (v > 20.f) ? v : log1pf(__expf(v));
  mm[g] = v * tanhf(sp);
}

// =================== X += (Hw+1)*Y + Hb ===================
__global__ __launch_bounds__(256) void align_apply(
    float* __restrict__ X, const float* __restrict__ Y,
    const float* __restrict__ H)
{
  int idx = blockIdx.x * 256 + threadIdx.x;  // rows*128 float4s
  int row = idx >> 7;
  int d4  = (idx & 127) * 4;
  int b   = row / NN;
  float4 y = *(const float4*)&Y[(size_t)row * DM + d4];
  float4 x = *(const float4*)&X[(size_t)row * DM + d4];
  const float* hw = H + (size_t)b * 1024 + d4;
  const float* hb = hw + 512;
  x.x += (hw[0] + 1.f) * y.x + hb[0];
  x.y += (hw[1] + 1.f) * y.y + hb[1];
  x.z += (hw[2] + 1.f) * y.z + hb[2];
  x.w += (hw[3] + 1.f) * y.w + hb[3];
  *(float4*)&X[(size_t)row * DM + d4] = x;
}

// =================== launch ===================
extern "C" void kernel_launch(void* const* d_in, const int* in_sizes, int n_in,
                              void* d_out, int out_size, void* d_ws, size_t ws_size,
                              hipStream_t stream)
{
  const float* tgt      = (const float*)d_in[0];
  const float* memory   = (const float*)d_in[1];
  const float* tvec     = (const float*)d_in[2];
  const float* qk_w     = (const float*)d_in[3];
  const float* v_w      = (const float*)d_in[4];
  const float* ds_lw    = (const float*)d_in[5];
  const float* ds_lb    = (const float*)d_in[6];
  const float* ta_in_w  = (const float*)d_in[7];
  const float* ta_in_b  = (const float*)d_in[8];
  const float* ta_out_w = (const float*)d_in[9];
  const float* ta_out_b = (const float*)d_in[10];
  const float* ca_in_w  = (const float*)d_in[11];
  const float* ca_in_b  = (const float*)d_in[12];
  const float* ca_out_w = (const float*)d_in[13];
  const float* ca_out_b = (const float*)d_in[14];
  const float* l1_w     = (const float*)d_in[15];
  const float* l1_b     = (const float*)d_in[16];
  const float* l2_w     = (const float*)d_in[17];
  const float* l2_b     = (const float*)d_in[18];
  const float* n1_g = (const float*)d_in[19]; const float* n1_b = (const float*)d_in[20];
  const float* n2_g = (const float*)d_in[21]; const float* n2_b = (const float*)d_in[22];
  const float* n3_g = (const float*)d_in[23]; const float* n3_b = (const float*)d_in[24];
  const float* n4_g = (const float*)d_in[25]; const float* n4_b = (const float*)d_in[26];
  const float* a1_w = (const float*)d_in[27]; const float* a1_b = (const float*)d_in[28];
  const float* a2_w = (const float*)d_in[29]; const float* a2_b = (const float*)d_in[30];
  const float* a3_w = (const float*)d_in[31]; const float* a3_b = (const float*)d_in[32];

  // ---- workspace layout (bytes) ----
  const size_t W_QKT = 1280ULL * 512 * 2;
  const size_t W_VT  = 640ULL  * 512 * 2;
  const size_t W_TAI = 1536ULL * 512 * 2;
  const size_t W_TAO = 512ULL  * 512 * 2;
  const size_t W_CAI = 1536ULL * 512 * 2;
  const size_t W_CAO = 512ULL  * 512 * 2;
  const size_t W_L1  = 2048ULL * 512 * 2;
  const size_t W_L2  = 512ULL  * 2048 * 2;
  const size_t W_MEM = (size_t)BB * NN * 512 * 2;
  const size_t fixedB = W_QKT + W_VT + W_TAI + W_TAO + W_CAI + W_CAO + W_L1 + W_L2 + W_MEM;
  // per-batch: XNh bf16[300][512] + SCR f32[300][1536] (aliases ds COMB /
  // self QKV / cross Q+KV / FFN bf16 hidden) + Vds f32[300][624] + Yb f32[300][512]
  // + MM[512] + Hb[1024]
  const size_t per_b = 300ULL*512*2 + 300ULL*1536*4 + 300ULL*624*4
                     + 300ULL*512*4 + 512ULL*4 + 1024ULL*4;   // 3,519,744
  int Bc = 128;
  while (Bc > 16 && fixedB + (size_t)Bc * per_b > ws_size) Bc >>= 1;
  const int rows = Bc * NN;
  const int mB   = (rows + 127) / 128;
  const int aB   = (Bc + 127) / 128;
  const int nchunks = BB / Bc;

  char* p = (char*)d_ws;
  unsigned short* qkTh  = (unsigned short*)p; p += W_QKT;
  unsigned short* vTh   = (unsigned short*)p; p += W_VT;
  unsigned short* taiWh = (unsigned short*)p; p += W_TAI;
  unsigned short* taoWh = (unsigned short*)p; p += W_TAO;
  unsigned short* caiWh = (unsigned short*)p; p += W_CAI;
  unsigned short* caoWh = (unsigned short*)p; p += W_CAO;
  unsigned short* l1Wh  = (unsigned short*)p; p += W_L1;
  unsigned short* l2Wh  = (unsigned short*)p; p += W_L2;
  unsigned short* memh  = (unsigned short*)p; p += W_MEM;
  unsigned short* XNh   = (unsigned short*)p; p += (size_t)rows * 512 * 2;
  float* SCR = (float*)p; p += (size_t)rows * 1536 * 4;   // multi-role scratch
  float* Vds = (float*)p; p += (size_t)rows * 624 * 4;
  float* Yb  = (float*)p; p += (size_t)rows * 512 * 4;
  float* MM  = (float*)p; p += (size_t)Bc * 512 * 4;
  float* Hb  = (float*)p;
  unsigned short* T2h = (unsigned short*)SCR;             // FFN hidden (bf16), aliases SCR

  dim3 thr(256);

  // ---- one-time weight / memory conversion ----
  transpose_bf16<<<dim3(40, 16), thr, 0, stream>>>(qk_w, qkTh, 512, 1248, 1280);
  transpose_bf16<<<dim3(20, 16), thr, 0, stream>>>(v_w,  vTh,  512, 624, 640);
  auto cvt = [&](const float* src, unsigned short* dst, size_t n) {
    int n4 = (int)(n / 4);
    cvt_bf16<<<dim3((n4 + 255) / 256), thr, 0, stream>>>(src, dst, n4);
  };
  cvt(ta_in_w,  taiWh, 1536ULL * 512);
  cvt(ta_out_w, taoWh, 512ULL * 512);
  cvt(ca_in_w,  caiWh, 1536ULL * 512);
  cvt(ca_out_w, caoWh, 512ULL * 512);
  cvt(l1_w,     l1Wh,  2048ULL * 512);
  cvt(l2_w,     l2Wh,  512ULL * 2048);
  cvt(memory,   memh,  (size_t)BB * NN * 512);

  for (int c = 0; c < nchunks; ++c) {
    const size_t roff = (size_t)c * Bc * NN * DM;
    const float* tgtC = tgt    + roff;
    const float* tC   = tvec   + (size_t)c * Bc * 512;
    const unsigned short* memhC = memh + roff;
    float*       XC   = (float*)d_out + roff;

    // ---- ds-attention branch: x = tgt + ds_attn(LN1(tgt)) ----
    ln_kernel<<<rows / 4, thr, 0, stream>>>(tgtC, n1_g, n1_b, XNh, rows);
    gemm_bb<0><<<dim3(10, mB), thr, 0, stream>>>(XNh, 512, qkTh, 512, nullptr, SCR, 1248, rows, 512, 1248);
    gemm_bb<0><<<dim3(5, mB),  thr, 0, stream>>>(XNh, 512, vTh,  512, nullptr, Vds, 624,  rows, 512, 624);
    ds_attn_kernel<<<rows / 2, thr, 0, stream>>>(SCR, Vds);
    gemm_bf16<3><<<dim3(4, mB), thr, 0, stream>>>(Vds, 624, ds_lw, 624, ds_lb, tgtC, 512, XC, 512, rows, 624, 512);

    // ---- self attention + align1 ----
    ln_kernel<<<rows / 4, thr, 0, stream>>>(XC, n2_g, n2_b, XNh, rows);
    gemm_bb<1><<<dim3(12, mB), thr, 0, stream>>>(XNh, 512, taiWh, 512, ta_in_b, SCR, 1536, rows, 512, 1536);
    mha_mfma<<<Bc * 8, 512, 0, stream>>>(SCR, 1536, 0, SCR, 1536, 512, 1024, XNh, 0.125f);
    gemm_bb<1><<<dim3(4, mB),  thr, 0, stream>>>(XNh, 512, taoWh, 512, ta_out_b, Yb, 512, rows, 512, 512);
    colmean_mish<<<Bc * 2, thr, 0, stream>>>(Yb, tC, MM);
    gemm_bf16<1><<<dim3(8, aB), thr, 0, stream>>>(MM, 512, a1_w, 512, a1_b, nullptr, 0, Hb, 1024, Bc, 512, 1024);
    align_apply<<<rows / 2, thr, 0, stream>>>(XC, Yb, Hb);

    // ---- cross attention + align2 ----
    ln_kernel<<<rows / 4, thr, 0, stream>>>(XC, n3_g, n3_b, XNh, rows);
    gemm_bb<1><<<dim3(4, mB),  thr, 0, stream>>>(XNh, 512, caiWh, 512, ca_in_b, SCR, 1536, rows, 512, 512);
    gemm_bb<1><<<dim3(8, mB),  thr, 0, stream>>>(memhC, 512, caiWh + 512 * 512, 512, ca_in_b + 512, SCR + 512, 1536, rows, 512, 1024);
    mha_mfma<<<Bc * 8, 512, 0, stream>>>(SCR, 1536, 0, SCR, 1536, 512, 1024, XNh, 0.125f);
    gemm_bb<1><<<dim3(4, mB),  thr, 0, stream>>>(XNh, 512, caoWh, 512, ca_out_b, Yb, 512, rows, 512, 512);
    colmean_mish<<<Bc * 2, thr, 0, stream>>>(Yb, tC, MM);
    gemm_bf16<1><<<dim3(8, aB), thr, 0, stream>>>(MM, 512, a2_w, 512, a2_b, nullptr, 0, Hb, 1024, Bc, 512, 1024);
    align_apply<<<rows / 2, thr, 0, stream>>>(XC, Yb, Hb);

    // ---- FFN (2x1024 halves) + align3 ----
    ln_kernel<<<rows / 4, thr, 0, stream>>>(XC, n4_g, n4_b, XNh, rows);
    gemm_bb<2><<<dim3(8, mB),  thr, 0, stream>>>(XNh, 512, l1Wh, 512, l1_b, T2h, 1024, rows, 512, 1024);
    gemm_bb<1><<<dim3(4, mB),  thr, 0, stream>>>(T2h, 1024, l2Wh, 2048, l2_b, Yb, 512, rows, 1024, 512);
    gemm_bb<2><<<dim3(8, mB),  thr, 0, stream>>>(XNh, 512, l1Wh + 1024 * 512, 512, l1_b + 1024, T2h, 1024, rows, 512, 1024);
    gemm_bb<4><<<dim3(4, mB),  thr, 0, stream>>>(T2h, 1024, l2Wh + 1024, 2048, nullptr, Yb, 512, rows, 1024, 512);
    colmean_mish<<<Bc * 2, thr, 0, stream>>>(Yb, tC, MM);
    gemm_bf16<1><<<dim3(8, aB), thr, 0, stream>>>(MM, 512, a3_w, 512, a3_b, nullptr, 0, Hb, 1024, Bc, 512, 1024);
    align_apply<<<rows / 2, thr, 0, stream>>>(XC, Yb, Hb);
  }
}

// Round 3
// 2320.693 us; speedup vs baseline: 1.4427x; 1.1539x over previous
//
#include <hip/hip_runtime.h>
#include <math.h>

#define DEV __device__ __forceinline__

// ---------------- problem dims ----------------
static constexpr int BB   = 128;     // batch
static constexpr int NN   = 300;     // tgt & memory seq len
static constexpr int DM   = 512;     // d_model

typedef __attribute__((ext_vector_type(8))) short short8;   // 8 bf16 = 4 VGPR
typedef __attribute__((ext_vector_type(4))) float f32x4;

// ---------------- helpers ----------------
DEV unsigned short f2bf(float f) {
  unsigned u = __float_as_uint(f);
  unsigned r = (u + 0x7fffu + ((u >> 16) & 1u)) >> 16;
  return (unsigned short)r;
}
DEV float bf2f(unsigned short s) { return __uint_as_float((unsigned)s << 16); }
DEV unsigned pack_bf16x2(float a, float b) {
  return (unsigned)f2bf(a) | ((unsigned)f2bf(b) << 16);
}
DEV unsigned pack_trunc(float a, float b) {   // truncate-to-bf16 pack (P in [0,1])
  return (__float_as_uint(a) >> 16) | (__float_as_uint(b) & 0xffff0000u);
}

// async global(16B/lane) -> LDS (wave-uniform base + lane*16)
DEV void gld16(const void* g, void* l) {
  __builtin_amdgcn_global_load_lds(
      (const __attribute__((address_space(1))) unsigned int*)g,
      (__attribute__((address_space(3))) unsigned int*)l,
      16, 0, 0);
}

// =================== LayerNorm (one wave per row of 512) -> bf16 out ===================
__global__ __launch_bounds__(256) void ln_kernel(
    const float* __restrict__ X, const float* __restrict__ g,
    const float* __restrict__ b, unsigned short* __restrict__ Y, int rows)
{
  int wv = threadIdx.x >> 6, lane = threadIdx.x & 63;
  int row = blockIdx.x * 4 + wv;
  if (row >= rows) return;
  const float* xp = X + (size_t)row * DM;
  float v[8]; float s = 0.f, s2 = 0.f;
#pragma unroll
  for (int j = 0; j < 8; j++) {
    v[j] = xp[lane + 64 * j]; s += v[j]; s2 += v[j] * v[j];
  }
#pragma unroll
  for (int o = 32; o >= 1; o >>= 1) { s += __shfl_xor(s, o); s2 += __shfl_xor(s2, o); }
  float mean = s * (1.f / 512.f);
  float var  = s2 * (1.f / 512.f) - mean * mean;
  float rstd = rsqrtf(var + 1e-5f);
  unsigned short* yp = Y + (size_t)row * DM;
#pragma unroll
  for (int j = 0; j < 8; j++) {
    int c = lane + 64 * j;
    yp[c] = f2bf((v[j] - mean) * rstd * g[c] + b[c]);
  }
}

// =================== f32 -> bf16 elementwise (weights / memory) ===================
__global__ __launch_bounds__(256) void cvt_bf16(
    const float* __restrict__ in, unsigned short* __restrict__ out, int n4)
{
  int i = blockIdx.x * 256 + threadIdx.x;
  if (i >= n4) return;
  float4 v = ((const float4*)in)[i];
  union { unsigned short s[4]; uint2 u; } o;
  o.s[0] = f2bf(v.x); o.s[1] = f2bf(v.y); o.s[2] = f2bf(v.z); o.s[3] = f2bf(v.w);
  *(uint2*)&out[(size_t)i * 4] = o.u;
}

// =================== f32 [R,C] -> bf16 [R,Cpad], pad cols zero ===================
__global__ __launch_bounds__(256) void cvt_pad_bf16(
    const float* __restrict__ in, unsigned short* __restrict__ out,
    int R, int C, int Cpad)
{
  int idx = blockIdx.x * 256 + threadIdx.x;
  int r = idx / Cpad, c = idx % Cpad;
  if (r >= R) return;
  out[idx] = (c < C) ? f2bf(in[(size_t)r * C + c]) : (unsigned short)0;
}

// =================== transpose f32 [R,C] -> bf16 [Cpad,R], pad rows zero ===================
__global__ __launch_bounds__(256) void transpose_bf16(
    const float* __restrict__ in, unsigned short* __restrict__ out,
    int R, int Ccols, int Cpad)
{
  __shared__ float t[32][33];
  int c0 = blockIdx.x * 32, r0 = blockIdx.y * 32;
  int x = threadIdx.x & 31, y = threadIdx.x >> 5;   // y in 0..7
#pragma unroll
  for (int dy = 0; dy < 32; dy += 8) {
    int r = r0 + y + dy, c = c0 + x;
    t[y + dy][x] = (r < R && c < Ccols) ? in[(size_t)r * Ccols + c] : 0.f;
  }
  __syncthreads();
#pragma unroll
  for (int dy = 0; dy < 32; dy += 8) {
    int c = c0 + y + dy, r = r0 + x;
    if (c < Cpad && r < R) out[(size_t)c * R + r] = f2bf(t[x][y + dy]);
  }
}

// =================== bf16-input GEMM, m97 structure + XCD swizzle ===================
// A bf16 [M,K] k-major, W bf16 [Npad,K] k-major (Npad mult of 128, pad rows zero).
// global_load_lds width-16 staging into linear LDS [128][32] per matrix.
// EPI: 0 f32, 1 f32+bias, 2 bf16 relu(+bias), 3 f32+bias+R, 5 bf16+bias, 6 bf16
template<int EPI>
__global__ __launch_bounds__(256) void gemm_bb(
    const unsigned short* __restrict__ A, int lda,
    const unsigned short* __restrict__ W, int ldw,
    const float* __restrict__ bias,
    const float* __restrict__ R, int ldr,
    void* __restrict__ Cv, int ldc,
    int M, int K, int NC)
{
  __shared__ __align__(16) unsigned short As[128 * 32];
  __shared__ __align__(16) unsigned short Bs[128 * 32];
  const int tid = threadIdx.x;
  const int wave = tid >> 6, lane = tid & 63;
  const int wr = wave >> 1, wc = wave & 1;
  const int quad = lane >> 4, l16 = lane & 15;

  // XCD-aware bijective remap (m204): contiguous tile chunk per XCD.
  const unsigned nx = gridDim.x, nwg = nx * gridDim.y;
  const unsigned orig = blockIdx.y * nx + blockIdx.x;
  const unsigned qq = nwg >> 3, rr = nwg & 7;
  const unsigned xcd = orig & 7, idx = orig >> 3;
  const unsigned swz = (xcd < rr) ? (xcd * (qq + 1) + idx)
                                  : (rr * (qq + 1) + (xcd - rr) * qq + idx);
  const int n0 = (int)(swz % nx) * 128;
  const int m0 = (int)(swz / nx) * 128;

  int ra = m0 + (tid >> 2);
  int ra0 = (ra      >= M) ? M - 1 : ra;
  int ra1 = (ra + 64 >= M) ? M - 1 : ra + 64;
  const unsigned short* a0 = A + (size_t)ra0 * lda + (tid & 3) * 8;
  const unsigned short* a1 = A + (size_t)ra1 * lda + (tid & 3) * 8;
  const unsigned short* b0 = W + (size_t)(n0 + (tid >> 2)) * ldw + (tid & 3) * 8;
  const unsigned short* b1 = b0 + (size_t)64 * ldw;
  unsigned short* dA0 = &As[wave * 512];           // issue0: bytes wave*1024
  unsigned short* dA1 = &As[2048 + wave * 512];    // issue1: +4096B
  unsigned short* dB0 = &Bs[wave * 512];
  unsigned short* dB1 = &Bs[2048 + wave * 512];

  f32x4 acc[4][4];
#pragma unroll
  for (int i = 0; i < 4; i++)
#pragma unroll
    for (int j = 0; j < 4; j++) acc[i][j] = (f32x4){0.f, 0.f, 0.f, 0.f};

  for (int k0 = 0; k0 < K; k0 += 32) {
    gld16(a0 + k0, dA0);
    gld16(a1 + k0, dA1);
    gld16(b0 + k0, dB0);
    gld16(b1 + k0, dB1);
    __syncthreads();                 // drains vmcnt -> LDS tiles complete
    short8 af[4], bq[4];
#pragma unroll
    for (int i = 0; i < 4; i++)
      af[i] = *(const short8*)&As[(wr * 64 + i * 16 + l16) * 32 + quad * 8];
#pragma unroll
    for (int j = 0; j < 4; j++)
      bq[j] = *(const short8*)&Bs[(wc * 64 + j * 16 + l16) * 32 + quad * 8];
#pragma unroll
    for (int i = 0; i < 4; i++)
#pragma unroll
      for (int j = 0; j < 4; j++)
        acc[i][j] = __builtin_amdgcn_mfma_f32_16x16x32_bf16(af[i], bq[j], acc[i][j], 0, 0, 0);
    __syncthreads();                 // all reads done before next overwrite
  }

#pragma unroll
  for (int i = 0; i < 4; i++) {
    int rbase = m0 + wr * 64 + i * 16 + quad * 4;
#pragma unroll
    for (int r = 0; r < 4; r++) {
      int row = rbase + r;
      if (row < M) {
        size_t rowc = (size_t)row * ldc;
#pragma unroll
        for (int j = 0; j < 4; j++) {
          int col = n0 + wc * 64 + j * 16 + l16;
          if (col < NC) {
            float e = acc[i][j][r];
            if (EPI == 1 || EPI == 2 || EPI == 3 || EPI == 5) e += bias[col];
            if (EPI == 3) e += R[(size_t)row * ldr + col];
            if (EPI == 2) {
              ((unsigned short*)Cv)[rowc + col] = f2bf(fmaxf(e, 0.f));
            } else if (EPI == 5 || EPI == 6) {
              ((unsigned short*)Cv)[rowc + col] = f2bf(e);
            } else {
              ((float*)Cv)[rowc + col] = e;
            }
          }
        }
      }
    }
  }
}

// =================== ds (kinematic-tree) attention, bf16 V ===================
__global__ __launch_bounds__(256) void ds_attn_kernel(
    const float* __restrict__ COMB, unsigned short* __restrict__ V)
{
  __shared__ float ks[4][2][24][6];
  __shared__ float vs[4][2][24][6];
  int wv = threadIdx.x >> 6, lane = threadIdx.x & 63;
  int half = lane >> 5, i = lane & 31;
  int u  = blockIdx.x * 4 + wv;     // head-pair unit
  int bn = u >> 1, hp = u & 1;
  int h  = hp * 2 + half;
  size_t cbase = (size_t)bn * 1248 + h * 156 + 3;
  size_t vbase = (size_t)bn * 640  + h * 156 + 3;

  float q[6];
  if (i < 24) {
#pragma unroll
    for (int j = 0; j < 6; j++) {
      q[j]                 = COMB[cbase + i * 6 + j];
      ks[wv][half][i][j]   = COMB[cbase + 624 + i * 6 + j];
      vs[wv][half][i][j]   = bf2f(V[vbase + i * 6 + j]);
    }
  } else {
#pragma unroll
    for (int j = 0; j < 6; j++) q[j] = 0.f;
  }
  __syncthreads();

  float p[24];
#pragma unroll
  for (int k = 0; k < 24; k++) p[k] = 0.f;

  if (i < 24) {
    float mx = -1e30f;
#pragma unroll
    for (int k = 0; k < 24; k++) {
      float s = 0.f;
#pragma unroll
      for (int j = 0; j < 6; j++) s += q[j] * ks[wv][half][k][j];
      s *= 0.4082482904638631f;   // 1/sqrt(6)
      p[k] = s; mx = fmaxf(mx, s);
    }
    float sum = 0.f;
#pragma unroll
    for (int k = 0; k < 24; k++) { p[k] = __expf(p[k] - mx); sum += p[k]; }
    float inv = 1.f / sum;
#pragma unroll
    for (int k = 0; k < 24; k++) p[k] *= inv;
  }

  {
    float c = p[0];
    float t;
    t = __shfl(c, 3, 32);  if (i == 6) c = (c + t) * 0.5f;
    t = __shfl(c, 6, 32);  if (i == 9) c = (c + t) * 0.5f;
    t = __shfl(c, 9, 32);  if (i >= 12 && i <= 14) c = (c + t) * 0.5f;
    int src = (i >= 3) ? (i - 3) : 0;
    t = __shfl(c, src, 32); if (i >= 15 && i <= 17) c = (c + t) * 0.5f;
    p[0] = c;
  }
  if (i == 0) {
    p[6]  = (p[6]  + p[3])  * 0.5f;
    p[9]  = (p[9]  + p[6])  * 0.5f;
    p[12] = (p[12] + p[9])  * 0.5f;
    p[13] = (p[13] + p[9])  * 0.5f;
    p[14] = (p[14] + p[9])  * 0.5f;
    p[16] = (p[16] + p[13]) * 0.5f;
    p[17] = (p[17] + p[14]) * 0.5f;
    p[15] = (p[15] + p[12]) * 0.5f;
  }

  if (i < 24) {
    float o[6] = {0.f, 0.f, 0.f, 0.f, 0.f, 0.f};
#pragma unroll
    for (int k = 0; k < 24; k++) {
#pragma unroll
      for (int j = 0; j < 6; j++) o[j] += p[k] * vs[wv][half][k][j];
    }
#pragma unroll
    for (int j = 0; j < 6; j++) V[vbase + i * 6 + j] = f2bf(o[j]);
  }
}

// =================== MFMA MHA (self & cross), dh=64, 8 heads, bf16 in/out ===================
__global__ __launch_bounds__(512) void mha_mfma(
    const unsigned short* __restrict__ Qp, int ldq, int qoff,
    const unsigned short* __restrict__ KVp, int ldkv, int koff, int voff,
    unsigned short* __restrict__ Op, float scale)
{
  __shared__ __align__(16) unsigned short Ksh[304 * 72];
  __shared__ __align__(16) unsigned short Vt[64 * 328];
  __shared__ __align__(16) unsigned short Pt[8][16 * 40];
  const int bh = blockIdx.x, b = bh >> 3, h = bh & 7;
  const int tid = threadIdx.x, wv = tid >> 6, lane = tid & 63;
  const int quad = lane >> 4, l16 = lane & 15;
  const size_t kbase = (size_t)b * NN * ldkv + koff + h * 64;
  const size_t vbase = (size_t)b * NN * ldkv + voff + h * 64;

  // ---- stage K: [300][64] bf16 -> Ksh[304][72] (rows 300..303 zero) ----
  for (int f = tid; f < 304 * 8; f += 512) {
    int rk = f >> 3, c8 = (f & 7) * 8;
    short8 w;
    if (rk < 300) {
      w = *(const short8*)(KVp + kbase + (size_t)rk * ldkv + c8);
    } else {
      union { uint4 u; short8 s; } z; z.u = make_uint4(0u, 0u, 0u, 0u); w = z.s;
    }
    *(short8*)&Ksh[rk * 72 + c8] = w;
  }
  // ---- stage V^T: Vt[d][seq], seq >= 300 zeroed ----
  for (int f = tid; f < 64 * 164; f += 512) {
    int d = f & 63, s0 = (f >> 6) * 2;
    unsigned w = 0u;
    if (s0 < 300) {
      unsigned short v0 = KVp[vbase + (size_t)s0 * ldkv + d];
      unsigned short v1 = (s0 + 1 < 300) ? KVp[vbase + (size_t)(s0 + 1) * ldkv + d]
                                         : (unsigned short)0;
      w = (unsigned)v0 | ((unsigned)v1 << 16);
    }
    *(unsigned*)&Vt[d * 328 + s0] = w;
  }
  __syncthreads();

  unsigned short* pt = &Pt[wv][0];

  for (int qt = wv; qt < 19; qt += 8) {
    int qrow = qt * 16 + l16; if (qrow > 299) qrow = 299;   // clamp; dup cols unused
    const unsigned short* qp = Qp + (size_t)(b * NN + qrow) * ldq + qoff + h * 64 + quad * 8;
    short8 qf[2];
    qf[0] = *(const short8*)(qp);
    qf[1] = *(const short8*)(qp + 32);

    // S' = K Q^T: rows = seq (19 tiles of 16), cols = qrow
    f32x4 sacc[19];
#pragma unroll
    for (int t = 0; t < 19; t++) {
      short8 k0 = *(const short8*)&Ksh[(t * 16 + l16) * 72 + quad * 8];
      short8 k1 = *(const short8*)&Ksh[(t * 16 + l16) * 72 + 32 + quad * 8];
      f32x4 a = (f32x4){0.f, 0.f, 0.f, 0.f};
      a = __builtin_amdgcn_mfma_f32_16x16x32_bf16(k0, qf[0], a, 0, 0, 0);
      a = __builtin_amdgcn_mfma_f32_16x16x32_bf16(k1, qf[1], a, 0, 0, 0);
      sacc[t] = a;
    }

    // softmax over seq for qrow = l16: in-lane over (t,r), cross-quad shfl
    float mx = -1e30f;
#pragma unroll
    for (int t = 0; t < 19; t++)
#pragma unroll
      for (int r = 0; r < 4; r++) mx = fmaxf(mx, sacc[t][r]);
    mx = fmaxf(mx, __shfl_xor(mx, 16));
    mx = fmaxf(mx, __shfl_xor(mx, 32));
    float sum = 0.f;
#pragma unroll
    for (int t = 0; t < 19; t++) {
#pragma unroll
      for (int r = 0; r < 4; r++) {
        float p = __expf((sacc[t][r] - mx) * scale);
        if (t == 18 && quad == 3) p = 0.f;     // seq 300..303 pad
        sacc[t][r] = p; sum += p;
      }
    }
    sum += __shfl_xor(sum, 16);
    sum += __shfl_xor(sum, 32);
    float inv = 1.f / sum;

    // PV: O[qrow][d] = sum_seq P[seq][qrow] V[seq][d]
    f32x4 oacc[4];
#pragma unroll
    for (int dt = 0; dt < 4; dt++) oacc[dt] = (f32x4){0.f, 0.f, 0.f, 0.f};
#pragma unroll
    for (int c = 0; c < 10; c++) {
#pragma unroll
      for (int tic = 0; tic < 2; tic++) {
        int t = 2 * c + tic;
        unsigned w0 = 0u, w1 = 0u;
        if (t < 19) {
          w0 = pack_trunc(sacc[t][0], sacc[t][1]);
          w1 = pack_trunc(sacc[t][2], sacc[t][3]);
        }
        *(unsigned*)&pt[l16 * 40 + tic * 16 + quad * 4]     = w0;
        *(unsigned*)&pt[l16 * 40 + tic * 16 + quad * 4 + 2] = w1;
      }
      short8 pa = *(const short8*)&pt[l16 * 40 + quad * 8];
#pragma unroll
      for (int dt = 0; dt < 4; dt++) {
        short8 vb = *(const short8*)&Vt[(dt * 16 + l16) * 328 + c * 32 + quad * 8];
        oacc[dt] = __builtin_amdgcn_mfma_f32_16x16x32_bf16(pa, vb, oacc[dt], 0, 0, 0);
      }
    }

    // epilogue: O rows = quad*4+r, cols = d = dt*16+l16; scale by 1/rowsum
#pragma unroll
    for (int r = 0; r < 4; r++) {
      int row = qt * 16 + quad * 4 + r;
      float iv = __shfl(inv, quad * 4 + r);
      if (row < 300) {
        unsigned short* op = Op + (size_t)(b * NN + row) * DM + h * 64 + l16;
#pragma unroll
        for (int dt = 0; dt < 4; dt++)
          op[dt * 16] = f2bf(oacc[dt][r] * iv);
      }
    }
  }
}

// =================== column mean over seq + mish(t + mean) -> bf16 ===================
__global__ __launch_bounds__(256) void colmean_mish(
    const float* __restrict__ Y, const float* __restrict__ tvec,
    unsigned short* __restrict__ mm)
{
  int g = blockIdx.x * 256 + threadIdx.x;
  int b = g >> 9, d = g & 511;
  const float* yp = Y + (size_t)b * NN * DM + d;
  float s = 0.f;
  for (int n = 0; n < NN; n++) s += yp[(size_t)n * DM];
  float v = tvec[g] + s * (1.f / 300.f);
  float sp = (v > 20.f) ? v : log1pf(__expf(v));
  mm[g] = f2bf(v * tanhf(sp));
}

// =================== X += (Hw+1)*Y + Hb ===================
__global__ __launch_bounds__(256) void align_apply(
    float* __restrict__ X, const float* __restrict__ Y,
    const float* __restrict__ H)
{
  int idx = blockIdx.x * 256 + threadIdx.x;  // rows*128 float4s
  int row = idx >> 7;
  int d4  = (idx & 127) * 4;
  int b   = row / NN;
  float4 y = *(const float4*)&Y[(size_t)row * DM + d4];
  float4 x = *(const float4*)&X[(size_t)row * DM + d4];
  const float* hw = H + (size_t)b * 1024 + d4;
  const float* hb = hw + 512;
  x.x += (hw[0] + 1.f) * y.x + hb[0];
  x.y += (hw[1] + 1.f) * y.y + hb[1];
  x.z += (hw[2] + 1.f) * y.z + hb[2];
  x.w += (hw[3] + 1.f) * y.w + hb[3];
  *(float4*)&X[(size_t)row * DM + d4] = x;
}

// =================== launch ===================
extern "C" void kernel_launch(void* const* d_in, const int* in_sizes, int n_in,
                              void* d_out, int out_size, void* d_ws, size_t ws_size,
                              hipStream_t stream)
{
  const float* tgt      = (const float*)d_in[0];
  const float* memory   = (const float*)d_in[1];
  const float* tvec     = (const float*)d_in[2];
  const float* qk_w     = (const float*)d_in[3];
  const float* v_w      = (const float*)d_in[4];
  const float* ds_lw    = (const float*)d_in[5];
  const float* ds_lb    = (const float*)d_in[6];
  const float* ta_in_w  = (const float*)d_in[7];
  const float* ta_in_b  = (const float*)d_in[8];
  const float* ta_out_w = (const float*)d_in[9];
  const float* ta_out_b = (const float*)d_in[10];
  const float* ca_in_w  = (const float*)d_in[11];
  const float* ca_in_b  = (const float*)d_in[12];
  const float* ca_out_w = (const float*)d_in[13];
  const float* ca_out_b = (const float*)d_in[14];
  const float* l1_w     = (const float*)d_in[15];
  const float* l1_b     = (const float*)d_in[16];
  const float* l2_w     = (const float*)d_in[17];
  const float* l2_b     = (const float*)d_in[18];
  const float* n1_g = (const float*)d_in[19]; const float* n1_b = (const float*)d_in[20];
  const float* n2_g = (const float*)d_in[21]; const float* n2_b = (const float*)d_in[22];
  const float* n3_g = (const float*)d_in[23]; const float* n3_b = (const float*)d_in[24];
  const float* n4_g = (const float*)d_in[25]; const float* n4_b = (const float*)d_in[26];
  const float* a1_w = (const float*)d_in[27]; const float* a1_b = (const float*)d_in[28];
  const float* a2_w = (const float*)d_in[29]; const float* a2_b = (const float*)d_in[30];
  const float* a3_w = (const float*)d_in[31]; const float* a3_b = (const float*)d_in[32];

  // ---- fixed workspace (bytes): bf16 weight copies ----
  const size_t W_QKT = 1280ULL * 512 * 2;
  const size_t W_VT  = 640ULL  * 512 * 2;
  const size_t W_TAI = 1536ULL * 512 * 2;
  const size_t W_TAO = 512ULL  * 512 * 2;
  const size_t W_CAI = 1536ULL * 512 * 2;
  const size_t W_CAO = 512ULL  * 512 * 2;
  const size_t W_L1  = 2048ULL * 512 * 2;
  const size_t W_L2  = 512ULL  * 2048 * 2;
  const size_t W_DSL = 512ULL  * 640 * 2;
  const size_t W_AX  = 1024ULL * 512 * 2;    // x3
  const size_t W_MEM = (size_t)BB * NN * 512 * 2;
  const size_t fixedB = W_QKT + W_VT + W_TAI + W_TAO + W_CAI + W_CAO
                      + W_L1 + W_L2 + W_DSL + 3 * W_AX + W_MEM;
  // per-batch: XNh bf16[300][512] + SCRB 300x4992B (COMB f32 1248 / QKV bf16 1536
  // / FFN bf16 2048) + Vdsh bf16[300][640] + Yb f32[300][512] + MMh bf16[512] + Hb f32[1024]
  const size_t per_b = 300ULL * (1024 + 4992 + 1280 + 2048) + 1024 + 4096;  // 2,808,320
  int Bc = 128;
  while (Bc > 16 && fixedB + (size_t)Bc * per_b > ws_size) Bc >>= 1;
  const int rows = Bc * NN;
  const int mB   = (rows + 127) / 128;
  const int aB   = (Bc + 127) / 128;
  const int nchunks = BB / Bc;

  char* p = (char*)d_ws;
  unsigned short* qkTh  = (unsigned short*)p; p += W_QKT;
  unsigned short* vTh   = (unsigned short*)p; p += W_VT;
  unsigned short* taiWh = (unsigned short*)p; p += W_TAI;
  unsigned short* taoWh = (unsigned short*)p; p += W_TAO;
  unsigned short* caiWh = (unsigned short*)p; p += W_CAI;
  unsigned short* caoWh = (unsigned short*)p; p += W_CAO;
  unsigned short* l1Wh  = (unsigned short*)p; p += W_L1;
  unsigned short* l2Wh  = (unsigned short*)p; p += W_L2;
  unsigned short* dslWh = (unsigned short*)p; p += W_DSL;
  unsigned short* a1Wh  = (unsigned short*)p; p += W_AX;
  unsigned short* a2Wh  = (unsigned short*)p; p += W_AX;
  unsigned short* a3Wh  = (unsigned short*)p; p += W_AX;
  unsigned short* memh  = (unsigned short*)p; p += W_MEM;
  unsigned short* XNh   = (unsigned short*)p; p += (size_t)rows * 512 * 2;
  char* SCRB = p;                             p += (size_t)rows * 4992;
  unsigned short* Vdsh  = (unsigned short*)p; p += (size_t)rows * 640 * 2;
  float* Yb  = (float*)p; p += (size_t)rows * 512 * 4;
  unsigned short* MMh = (unsigned short*)p;   p += (size_t)Bc * 512 * 2;
  float* Hb  = (float*)p;

  float* COMB = (float*)SCRB;                  // [rows][1248] f32
  unsigned short* QKVh = (unsigned short*)SCRB;// [rows][1536] bf16
  unsigned short* T2h  = (unsigned short*)SCRB;// [rows][2048] bf16

  dim3 thr(256);

  // ---- one-time weight / memory conversion ----
  transpose_bf16<<<dim3(40, 16), thr, 0, stream>>>(qk_w, qkTh, 512, 1248, 1280);
  transpose_bf16<<<dim3(20, 16), thr, 0, stream>>>(v_w,  vTh,  512, 624, 640);
  cvt_pad_bf16<<<dim3(512 * 640 / 256), thr, 0, stream>>>(ds_lw, dslWh, 512, 624, 640);
  auto cvt = [&](const float* src, unsigned short* dst, size_t n) {
    int n4 = (int)(n / 4);
    cvt_bf16<<<dim3((n4 + 255) / 256), thr, 0, stream>>>(src, dst, n4);
  };
  cvt(ta_in_w,  taiWh, 1536ULL * 512);
  cvt(ta_out_w, taoWh, 512ULL * 512);
  cvt(ca_in_w,  caiWh, 1536ULL * 512);
  cvt(ca_out_w, caoWh, 512ULL * 512);
  cvt(l1_w,     l1Wh,  2048ULL * 512);
  cvt(l2_w,     l2Wh,  512ULL * 2048);
  cvt(a1_w,     a1Wh,  1024ULL * 512);
  cvt(a2_w,     a2Wh,  1024ULL * 512);
  cvt(a3_w,     a3Wh,  1024ULL * 512);
  cvt(memory,   memh,  (size_t)BB * NN * 512);

  for (int c = 0; c < nchunks; ++c) {
    const size_t roff = (size_t)c * Bc * NN * DM;
    const float* tgtC = tgt    + roff;
    const float* tC   = tvec   + (size_t)c * Bc * 512;
    const unsigned short* memhC = memh + roff;
    float*       XC   = (float*)d_out + roff;

    // ---- ds-attention branch: x = tgt + ds_attn(LN1(tgt)) ----
    ln_kernel<<<rows / 4, thr, 0, stream>>>(tgtC, n1_g, n1_b, XNh, rows);
    gemm_bb<0><<<dim3(10, mB), thr, 0, stream>>>(XNh, 512, qkTh, 512, nullptr, nullptr, 0, COMB, 1248, rows, 512, 1248);
    gemm_bb<6><<<dim3(5, mB),  thr, 0, stream>>>(XNh, 512, vTh,  512, nullptr, nullptr, 0, Vdsh, 640,  rows, 512, 640);
    ds_attn_kernel<<<rows / 2, thr, 0, stream>>>(COMB, Vdsh);
    gemm_bb<3><<<dim3(4, mB),  thr, 0, stream>>>(Vdsh, 640, dslWh, 640, ds_lb, tgtC, 512, XC, 512, rows, 640, 512);

    // ---- self attention + align1 ----
    ln_kernel<<<rows / 4, thr, 0, stream>>>(XC, n2_g, n2_b, XNh, rows);
    gemm_bb<5><<<dim3(12, mB), thr, 0, stream>>>(XNh, 512, taiWh, 512, ta_in_b, nullptr, 0, QKVh, 1536, rows, 512, 1536);
    mha_mfma<<<Bc * 8, 512, 0, stream>>>(QKVh, 1536, 0, QKVh, 1536, 512, 1024, XNh, 0.125f);
    gemm_bb<1><<<dim3(4, mB),  thr, 0, stream>>>(XNh, 512, taoWh, 512, ta_out_b, nullptr, 0, Yb, 512, rows, 512, 512);
    colmean_mish<<<Bc * 2, thr, 0, stream>>>(Yb, tC, MMh);
    gemm_bb<1><<<dim3(8, aB),  thr, 0, stream>>>(MMh, 512, a1Wh, 512, a1_b, nullptr, 0, Hb, 1024, Bc, 512, 1024);
    align_apply<<<rows / 2, thr, 0, stream>>>(XC, Yb, Hb);

    // ---- cross attention + align2 ----
    ln_kernel<<<rows / 4, thr, 0, stream>>>(XC, n3_g, n3_b, XNh, rows);
    gemm_bb<5><<<dim3(4, mB),  thr, 0, stream>>>(XNh, 512, caiWh, 512, ca_in_b, nullptr, 0, QKVh, 1536, rows, 512, 512);
    gemm_bb<5><<<dim3(8, mB),  thr, 0, stream>>>(memhC, 512, caiWh + 512 * 512, 512, ca_in_b + 512, nullptr, 0, QKVh + 512, 1536, rows, 512, 1024);
    mha_mfma<<<Bc * 8, 512, 0, stream>>>(QKVh, 1536, 0, QKVh, 1536, 512, 1024, XNh, 0.125f);
    gemm_bb<1><<<dim3(4, mB),  thr, 0, stream>>>(XNh, 512, caoWh, 512, ca_out_b, nullptr, 0, Yb, 512, rows, 512, 512);
    colmean_mish<<<Bc * 2, thr, 0, stream>>>(Yb, tC, MMh);
    gemm_bb<1><<<dim3(8, aB),  thr, 0, stream>>>(MMh, 512, a2Wh, 512, a2_b, nullptr, 0, Hb, 1024, Bc, 512, 1024);
    align_apply<<<rows / 2, thr, 0, stream>>>(XC, Yb, Hb);

    // ---- FFN (merged N=2048, K=2048) + align3 ----
    ln_kernel<<<rows / 4, thr, 0, stream>>>(XC, n4_g, n4_b, XNh, rows);
    gemm_bb<2><<<dim3(16, mB), thr, 0, stream>>>(XNh, 512, l1Wh, 512, l1_b, nullptr, 0, T2h, 2048, rows, 512, 2048);
    gemm_bb<1><<<dim3(4, mB),  thr, 0, stream>>>(T2h, 2048, l2Wh, 2048, l2_b, nullptr, 0, Yb, 512, rows, 2048, 512);
    colmean_mish<<<Bc * 2, thr, 0, stream>>>(Yb, tC, MMh);
    gemm_bb<1><<<dim3(8, aB),  thr, 0, stream>>>(MMh, 512, a3Wh, 512, a3_b, nullptr, 0, Hb, 1024, Bc, 512, 1024);
    align_apply<<<rows / 2, thr, 0, stream>>>(XC, Yb, Hb);
  }
}

// Round 4
// 2294.777 us; speedup vs baseline: 1.4590x; 1.0113x over previous
//
#include <hip/hip_runtime.h>
#include <math.h>

#define DEV __device__ __forceinline__

// ---------------- problem dims ----------------
static constexpr int BB   = 128;     // batch
static constexpr int NN   = 300;     // tgt & memory seq len
static constexpr int DM   = 512;     // d_model

typedef __attribute__((ext_vector_type(8))) short short8;   // 8 bf16 = 4 VGPR
typedef __attribute__((ext_vector_type(4))) float f32x4;

// ---------------- helpers ----------------
DEV unsigned short f2bf(float f) {
  unsigned u = __float_as_uint(f);
  unsigned r = (u + 0x7fffu + ((u >> 16) & 1u)) >> 16;
  return (unsigned short)r;
}
DEV float bf2f(unsigned short s) { return __uint_as_float((unsigned)s << 16); }
DEV unsigned pack_bf16x2(float a, float b) {
  return (unsigned)f2bf(a) | ((unsigned)f2bf(b) << 16);
}
DEV unsigned pack_trunc(float a, float b) {   // truncate-to-bf16 pack (P in [0,1])
  return (__float_as_uint(a) >> 16) | (__float_as_uint(b) & 0xffff0000u);
}

// async global(16B/lane) -> LDS (wave-uniform base + lane*16)
DEV void gld16(const void* g, void* l) {
  __builtin_amdgcn_global_load_lds(
      (const __attribute__((address_space(1))) unsigned int*)g,
      (__attribute__((address_space(3))) unsigned int*)l,
      16, 0, 0);
}

// =================== LayerNorm (one wave per row of 512) -> bf16 out ===================
__global__ __launch_bounds__(256) void ln_kernel(
    const float* __restrict__ X, const float* __restrict__ g,
    const float* __restrict__ b, unsigned short* __restrict__ Y, int rows)
{
  int wv = threadIdx.x >> 6, lane = threadIdx.x & 63;
  int row = blockIdx.x * 4 + wv;
  if (row >= rows) return;
  const float* xp = X + (size_t)row * DM;
  float v[8]; float s = 0.f, s2 = 0.f;
#pragma unroll
  for (int j = 0; j < 8; j++) {
    v[j] = xp[lane + 64 * j]; s += v[j]; s2 += v[j] * v[j];
  }
#pragma unroll
  for (int o = 32; o >= 1; o >>= 1) { s += __shfl_xor(s, o); s2 += __shfl_xor(s2, o); }
  float mean = s * (1.f / 512.f);
  float var  = s2 * (1.f / 512.f) - mean * mean;
  float rstd = rsqrtf(var + 1e-5f);
  unsigned short* yp = Y + (size_t)row * DM;
#pragma unroll
  for (int j = 0; j < 8; j++) {
    int c = lane + 64 * j;
    yp[c] = f2bf((v[j] - mean) * rstd * g[c] + b[c]);
  }
}

// =================== fused X += (Hw+1)Y + Hb  ->  LN -> bf16 ===================
// one wave per row; writes updated X (f32) and LN(X') (bf16)
__global__ __launch_bounds__(256) void align_ln(
    float* __restrict__ X, const float* __restrict__ Y,
    const float* __restrict__ H,
    const float* __restrict__ g, const float* __restrict__ bb,
    unsigned short* __restrict__ XN)
{
  int wv = threadIdx.x >> 6, lane = threadIdx.x & 63;
  int row = blockIdx.x * 4 + wv;
  int b = row / NN;
  float* xp = X + (size_t)row * DM;
  const float* yp = Y + (size_t)row * DM;
  const float* hw = H + (size_t)b * 1024;
  const float* hb = hw + 512;
  float v[8]; float s = 0.f, s2 = 0.f;
#pragma unroll
  for (int j = 0; j < 8; j++) {
    int c = lane + 64 * j;
    float xv = xp[c] + (hw[c] + 1.f) * yp[c] + hb[c];
    v[j] = xv; s += xv; s2 += xv * xv;
  }
#pragma unroll
  for (int j = 0; j < 8; j++) xp[lane + 64 * j] = v[j];
#pragma unroll
  for (int o = 32; o >= 1; o >>= 1) { s += __shfl_xor(s, o); s2 += __shfl_xor(s2, o); }
  float mean = s * (1.f / 512.f);
  float var  = s2 * (1.f / 512.f) - mean * mean;
  float rstd = rsqrtf(var + 1e-5f);
  unsigned short* yn = XN + (size_t)row * DM;
#pragma unroll
  for (int j = 0; j < 8; j++) {
    int c = lane + 64 * j;
    yn[c] = f2bf((v[j] - mean) * rstd * g[c] + bb[c]);
  }
}

// =================== f32 -> bf16 elementwise (weights / memory) ===================
__global__ __launch_bounds__(256) void cvt_bf16(
    const float* __restrict__ in, unsigned short* __restrict__ out, int n4)
{
  int i = blockIdx.x * 256 + threadIdx.x;
  if (i >= n4) return;
  float4 v = ((const float4*)in)[i];
  union { unsigned short s[4]; uint2 u; } o;
  o.s[0] = f2bf(v.x); o.s[1] = f2bf(v.y); o.s[2] = f2bf(v.z); o.s[3] = f2bf(v.w);
  *(uint2*)&out[(size_t)i * 4] = o.u;
}

// =================== f32 [R,C] -> bf16 [R,Cpad], pad cols zero ===================
__global__ __launch_bounds__(256) void cvt_pad_bf16(
    const float* __restrict__ in, unsigned short* __restrict__ out,
    int R, int C, int Cpad)
{
  int idx = blockIdx.x * 256 + threadIdx.x;
  int r = idx / Cpad, c = idx % Cpad;
  if (r >= R) return;
  out[idx] = (c < C) ? f2bf(in[(size_t)r * C + c]) : (unsigned short)0;
}

// =================== transpose f32 [R,C] -> bf16 [Cpad,R], pad rows zero ===================
__global__ __launch_bounds__(256) void transpose_bf16(
    const float* __restrict__ in, unsigned short* __restrict__ out,
    int R, int Ccols, int Cpad)
{
  __shared__ float t[32][33];
  int c0 = blockIdx.x * 32, r0 = blockIdx.y * 32;
  int x = threadIdx.x & 31, y = threadIdx.x >> 5;   // y in 0..7
#pragma unroll
  for (int dy = 0; dy < 32; dy += 8) {
    int r = r0 + y + dy, c = c0 + x;
    t[y + dy][x] = (r < R && c < Ccols) ? in[(size_t)r * Ccols + c] : 0.f;
  }
  __syncthreads();
#pragma unroll
  for (int dy = 0; dy < 32; dy += 8) {
    int c = c0 + y + dy, r = r0 + x;
    if (c < Cpad && r < R) out[(size_t)c * R + r] = f2bf(t[x][y + dy]);
  }
}

// =================== bf16-input GEMM, m97 structure + XCD swizzle ===================
// A bf16 [M,K] k-major, W bf16 [Npad,K] k-major (Npad mult of 128, pad rows zero).
// global_load_lds width-16 staging into linear LDS [128][32] per matrix.
// EPI: 0 f32, 1 f32+bias, 2 bf16 relu(+bias), 3 f32+bias+R, 5 bf16+bias, 6 bf16
template<int EPI>
__global__ __launch_bounds__(256) void gemm_bb(
    const unsigned short* __restrict__ A, int lda,
    const unsigned short* __restrict__ W, int ldw,
    const float* __restrict__ bias,
    const float* __restrict__ R, int ldr,
    void* __restrict__ Cv, int ldc,
    int M, int K, int NC)
{
  __shared__ __align__(16) unsigned short As[128 * 32];
  __shared__ __align__(16) unsigned short Bs[128 * 32];
  const int tid = threadIdx.x;
  const int wave = tid >> 6, lane = tid & 63;
  const int wr = wave >> 1, wc = wave & 1;
  const int quad = lane >> 4, l16 = lane & 15;

  // XCD-aware bijective remap (m204): contiguous tile chunk per XCD.
  const unsigned nx = gridDim.x, nwg = nx * gridDim.y;
  const unsigned orig = blockIdx.y * nx + blockIdx.x;
  const unsigned qq = nwg >> 3, rr = nwg & 7;
  const unsigned xcd = orig & 7, idx = orig >> 3;
  const unsigned swz = (xcd < rr) ? (xcd * (qq + 1) + idx)
                                  : (rr * (qq + 1) + (xcd - rr) * qq + idx);
  const int n0 = (int)(swz % nx) * 128;
  const int m0 = (int)(swz / nx) * 128;

  int ra = m0 + (tid >> 2);
  int ra0 = (ra      >= M) ? M - 1 : ra;
  int ra1 = (ra + 64 >= M) ? M - 1 : ra + 64;
  const unsigned short* a0 = A + (size_t)ra0 * lda + (tid & 3) * 8;
  const unsigned short* a1 = A + (size_t)ra1 * lda + (tid & 3) * 8;
  const unsigned short* b0 = W + (size_t)(n0 + (tid >> 2)) * ldw + (tid & 3) * 8;
  const unsigned short* b1 = b0 + (size_t)64 * ldw;
  unsigned short* dA0 = &As[wave * 512];           // issue0: bytes wave*1024
  unsigned short* dA1 = &As[2048 + wave * 512];    // issue1: +4096B
  unsigned short* dB0 = &Bs[wave * 512];
  unsigned short* dB1 = &Bs[2048 + wave * 512];

  f32x4 acc[4][4];
#pragma unroll
  for (int i = 0; i < 4; i++)
#pragma unroll
    for (int j = 0; j < 4; j++) acc[i][j] = (f32x4){0.f, 0.f, 0.f, 0.f};

  for (int k0 = 0; k0 < K; k0 += 32) {
    gld16(a0 + k0, dA0);
    gld16(a1 + k0, dA1);
    gld16(b0 + k0, dB0);
    gld16(b1 + k0, dB1);
    __syncthreads();                 // drains vmcnt -> LDS tiles complete
    short8 af[4], bq[4];
#pragma unroll
    for (int i = 0; i < 4; i++)
      af[i] = *(const short8*)&As[(wr * 64 + i * 16 + l16) * 32 + quad * 8];
#pragma unroll
    for (int j = 0; j < 4; j++)
      bq[j] = *(const short8*)&Bs[(wc * 64 + j * 16 + l16) * 32 + quad * 8];
#pragma unroll
    for (int i = 0; i < 4; i++)
#pragma unroll
      for (int j = 0; j < 4; j++)
        acc[i][j] = __builtin_amdgcn_mfma_f32_16x16x32_bf16(af[i], bq[j], acc[i][j], 0, 0, 0);
    __syncthreads();                 // all reads done before next overwrite
  }

#pragma unroll
  for (int i = 0; i < 4; i++) {
    int rbase = m0 + wr * 64 + i * 16 + quad * 4;
#pragma unroll
    for (int r = 0; r < 4; r++) {
      int row = rbase + r;
      if (row < M) {
        size_t rowc = (size_t)row * ldc;
#pragma unroll
        for (int j = 0; j < 4; j++) {
          int col = n0 + wc * 64 + j * 16 + l16;
          if (col < NC) {
            float e = acc[i][j][r];
            if (EPI == 1 || EPI == 2 || EPI == 3 || EPI == 5) e += bias[col];
            if (EPI == 3) e += R[(size_t)row * ldr + col];
            if (EPI == 2) {
              ((unsigned short*)Cv)[rowc + col] = f2bf(fmaxf(e, 0.f));
            } else if (EPI == 5 || EPI == 6) {
              ((unsigned short*)Cv)[rowc + col] = f2bf(e);
            } else {
              ((float*)Cv)[rowc + col] = e;
            }
          }
        }
      }
    }
  }
}

// =================== ds (kinematic-tree) attention, bf16 V ===================
__global__ __launch_bounds__(256) void ds_attn_kernel(
    const float* __restrict__ COMB, unsigned short* __restrict__ V)
{
  __shared__ float ks[4][2][24][6];
  __shared__ float vs[4][2][24][6];
  int wv = threadIdx.x >> 6, lane = threadIdx.x & 63;
  int half = lane >> 5, i = lane & 31;
  int u  = blockIdx.x * 4 + wv;     // head-pair unit
  int bn = u >> 1, hp = u & 1;
  int h  = hp * 2 + half;
  size_t cbase = (size_t)bn * 1248 + h * 156 + 3;
  size_t vbase = (size_t)bn * 640  + h * 156 + 3;

  float q[6];
  if (i < 24) {
#pragma unroll
    for (int j = 0; j < 6; j++) {
      q[j]                 = COMB[cbase + i * 6 + j];
      ks[wv][half][i][j]   = COMB[cbase + 624 + i * 6 + j];
      vs[wv][half][i][j]   = bf2f(V[vbase + i * 6 + j]);
    }
  } else {
#pragma unroll
    for (int j = 0; j < 6; j++) q[j] = 0.f;
  }
  __syncthreads();

  float p[24];
#pragma unroll
  for (int k = 0; k < 24; k++) p[k] = 0.f;

  if (i < 24) {
    float mx = -1e30f;
#pragma unroll
    for (int k = 0; k < 24; k++) {
      float s = 0.f;
#pragma unroll
      for (int j = 0; j < 6; j++) s += q[j] * ks[wv][half][k][j];
      s *= 0.4082482904638631f;   // 1/sqrt(6)
      p[k] = s; mx = fmaxf(mx, s);
    }
    float sum = 0.f;
#pragma unroll
    for (int k = 0; k < 24; k++) { p[k] = __expf(p[k] - mx); sum += p[k]; }
    float inv = 1.f / sum;
#pragma unroll
    for (int k = 0; k < 24; k++) p[k] *= inv;
  }

  {
    float c = p[0];
    float t;
    t = __shfl(c, 3, 32);  if (i == 6) c = (c + t) * 0.5f;
    t = __shfl(c, 6, 32);  if (i == 9) c = (c + t) * 0.5f;
    t = __shfl(c, 9, 32);  if (i >= 12 && i <= 14) c = (c + t) * 0.5f;
    int src = (i >= 3) ? (i - 3) : 0;
    t = __shfl(c, src, 32); if (i >= 15 && i <= 17) c = (c + t) * 0.5f;
    p[0] = c;
  }
  if (i == 0) {
    p[6]  = (p[6]  + p[3])  * 0.5f;
    p[9]  = (p[9]  + p[6])  * 0.5f;
    p[12] = (p[12] + p[9])  * 0.5f;
    p[13] = (p[13] + p[9])  * 0.5f;
    p[14] = (p[14] + p[9])  * 0.5f;
    p[16] = (p[16] + p[13]) * 0.5f;
    p[17] = (p[17] + p[14]) * 0.5f;
    p[15] = (p[15] + p[12]) * 0.5f;
  }

  if (i < 24) {
    float o[6] = {0.f, 0.f, 0.f, 0.f, 0.f, 0.f};
#pragma unroll
    for (int k = 0; k < 24; k++) {
#pragma unroll
      for (int j = 0; j < 6; j++) o[j] += p[k] * vs[wv][half][k][j];
    }
#pragma unroll
    for (int j = 0; j < 6; j++) V[vbase + i * 6 + j] = f2bf(o[j]);
  }
}

// =================== MFMA MHA (self & cross), dh=64, 8 heads, bf16 in/out ===================
// Q staged in LDS (removes per-tile global latency); O written via per-wave
// LDS transpose -> 16B/lane contiguous stores (kills write amplification).
__global__ __launch_bounds__(512) void mha_mfma(
    const unsigned short* __restrict__ Qp, int ldq, int qoff,
    const unsigned short* __restrict__ KVp, int ldkv, int koff, int voff,
    unsigned short* __restrict__ Op, float scale)
{
  __shared__ __align__(16) unsigned short Ksh[304 * 72];
  __shared__ __align__(16) unsigned short Qsh[304 * 72];
  __shared__ __align__(16) unsigned short Vt[64 * 328];
  __shared__ __align__(16) unsigned short Pt[8][16 * 68];
  const int bh = blockIdx.x, b = bh >> 3, h = bh & 7;
  const int tid = threadIdx.x, wv = tid >> 6, lane = tid & 63;
  const int quad = lane >> 4, l16 = lane & 15;
  const size_t kbase = (size_t)b * NN * ldkv + koff + h * 64;
  const size_t vbase = (size_t)b * NN * ldkv + voff + h * 64;
  const size_t qbase = (size_t)b * NN * ldq  + qoff + h * 64;

  // ---- stage K and Q: [300][64] bf16 -> [304][72] (rows 300..303 zero) ----
  for (int f = tid; f < 304 * 8; f += 512) {
    int rk = f >> 3, c8 = (f & 7) * 8;
    short8 wk, wq;
    if (rk < 300) {
      wk = *(const short8*)(KVp + kbase + (size_t)rk * ldkv + c8);
      wq = *(const short8*)(Qp  + qbase + (size_t)rk * ldq  + c8);
    } else {
      union { uint4 u; short8 s; } z; z.u = make_uint4(0u, 0u, 0u, 0u);
      wk = z.s; wq = z.s;
    }
    *(short8*)&Ksh[rk * 72 + c8] = wk;
    *(short8*)&Qsh[rk * 72 + c8] = wq;
  }
  // ---- stage V^T: Vt[d][seq], seq >= 300 zeroed ----
  for (int f = tid; f < 64 * 164; f += 512) {
    int d = f & 63, s0 = (f >> 6) * 2;
    unsigned w = 0u;
    if (s0 < 300) {
      unsigned short v0 = KVp[vbase + (size_t)s0 * ldkv + d];
      unsigned short v1 = (s0 + 1 < 300) ? KVp[vbase + (size_t)(s0 + 1) * ldkv + d]
                                         : (unsigned short)0;
      w = (unsigned)v0 | ((unsigned)v1 << 16);
    }
    *(unsigned*)&Vt[d * 328 + s0] = w;
  }
  __syncthreads();

  unsigned short* pt = &Pt[wv][0];

  for (int qt = wv; qt < 19; qt += 8) {
    int qr = qt * 16 + l16;                       // 0..303; pad rows are zero
    short8 qf[2];
    qf[0] = *(const short8*)&Qsh[qr * 72 + quad * 8];
    qf[1] = *(const short8*)&Qsh[qr * 72 + 32 + quad * 8];

    // S' = K Q^T: rows = seq (19 tiles of 16), cols = qrow
    f32x4 sacc[19];
#pragma unroll
    for (int t = 0; t < 19; t++) {
      short8 k0 = *(const short8*)&Ksh[(t * 16 + l16) * 72 + quad * 8];
      short8 k1 = *(const short8*)&Ksh[(t * 16 + l16) * 72 + 32 + quad * 8];
      f32x4 a = (f32x4){0.f, 0.f, 0.f, 0.f};
      a = __builtin_amdgcn_mfma_f32_16x16x32_bf16(k0, qf[0], a, 0, 0, 0);
      a = __builtin_amdgcn_mfma_f32_16x16x32_bf16(k1, qf[1], a, 0, 0, 0);
      sacc[t] = a;
    }

    // softmax over seq for qrow = l16: in-lane over (t,r), cross-quad shfl
    float mx = -1e30f;
#pragma unroll
    for (int t = 0; t < 19; t++)
#pragma unroll
      for (int r = 0; r < 4; r++) mx = fmaxf(mx, sacc[t][r]);
    mx = fmaxf(mx, __shfl_xor(mx, 16));
    mx = fmaxf(mx, __shfl_xor(mx, 32));
    float sum = 0.f;
#pragma unroll
    for (int t = 0; t < 19; t++) {
#pragma unroll
      for (int r = 0; r < 4; r++) {
        float p = __expf((sacc[t][r] - mx) * scale);
        if (t == 18 && quad == 3) p = 0.f;     // seq 300..303 pad
        sacc[t][r] = p; sum += p;
      }
    }
    sum += __shfl_xor(sum, 16);
    sum += __shfl_xor(sum, 32);
    float inv = 1.f / sum;

    // PV: O[qrow][d] = sum_seq P[seq][qrow] V[seq][d]
    f32x4 oacc[4];
#pragma unroll
    for (int dt = 0; dt < 4; dt++) oacc[dt] = (f32x4){0.f, 0.f, 0.f, 0.f};
#pragma unroll
    for (int c = 0; c < 10; c++) {
#pragma unroll
      for (int tic = 0; tic < 2; tic++) {
        int t = 2 * c + tic;
        unsigned w0 = 0u, w1 = 0u;
        if (t < 19) {
          w0 = pack_trunc(sacc[t][0], sacc[t][1]);
          w1 = pack_trunc(sacc[t][2], sacc[t][3]);
        }
        *(unsigned*)&pt[l16 * 68 + tic * 16 + quad * 4]     = w0;
        *(unsigned*)&pt[l16 * 68 + tic * 16 + quad * 4 + 2] = w1;
      }
      short8 pa = *(const short8*)&pt[l16 * 68 + quad * 8];
#pragma unroll
      for (int dt = 0; dt < 4; dt++) {
        short8 vb = *(const short8*)&Vt[(dt * 16 + l16) * 328 + c * 32 + quad * 8];
        oacc[dt] = __builtin_amdgcn_mfma_f32_16x16x32_bf16(pa, vb, oacc[dt], 0, 0, 0);
      }
    }

    // epilogue: transpose through Pt, then 16B/lane contiguous stores.
    // write: lane (quad,l16) holds rows quad*4+r, cols dt*16+l16
#pragma unroll
    for (int r = 0; r < 4; r++) {
      float iv = __shfl(inv, quad * 4 + r);
#pragma unroll
      for (int dt = 0; dt < 4; dt++)
        pt[(quad * 4 + r) * 68 + dt * 16 + l16] = f2bf(oacc[dt][r] * iv);
    }
    // read back: 2 reps x 64 lanes = 128 uint4; 8 lanes cover a 128B row
#pragma unroll
    for (int rep = 0; rep < 2; rep++) {
      int idx = rep * 64 + lane;
      int rl = idx >> 3, seg = idx & 7;
      int row = qt * 16 + rl;
      uint4 w = *(const uint4*)&pt[rl * 68 + seg * 8];
      if (row < 300)
        *(uint4*)(Op + (size_t)(b * NN + row) * DM + h * 64 + seg * 8) = w;
    }
  }
}

// =================== column mean over seq + mish(t + mean) -> bf16 ===================
__global__ __launch_bounds__(256) void colmean_mish(
    const float* __restrict__ Y, const float* __restrict__ tvec,
    unsigned short* __restrict__ mm)
{
  int g = blockIdx.x * 256 + threadIdx.x;
  int b = g >> 9, d = g & 511;
  const float* yp = Y + (size_t)b * NN * DM + d;
  float s = 0.f;
  for (int n = 0; n < NN; n++) s += yp[(size_t)n * DM];
  float v = tvec[g] + s * (1.f / 300.f);
  float sp = (v > 20.f) ? v : log1pf(__expf(v));
  mm[g] = f2bf(v * tanhf(sp));
}

// =================== X += (Hw+1)*Y + Hb ===================
__global__ __launch_bounds__(256) void align_apply(
    float* __restrict__ X, const float* __restrict__ Y,
    const float* __restrict__ H)
{
  int idx = blockIdx.x * 256 + threadIdx.x;  // rows*128 float4s
  int row = idx >> 7;
  int d4  = (idx & 127) * 4;
  int b   = row / NN;
  float4 y = *(const float4*)&Y[(size_t)row * DM + d4];
  float4 x = *(const float4*)&X[(size_t)row * DM + d4];
  const float* hw = H + (size_t)b * 1024 + d4;
  const float* hb = hw + 512;
  x.x += (hw[0] + 1.f) * y.x + hb[0];
  x.y += (hw[1] + 1.f) * y.y + hb[1];
  x.z += (hw[2] + 1.f) * y.z + hb[2];
  x.w += (hw[3] + 1.f) * y.w + hb[3];
  *(float4*)&X[(size_t)row * DM + d4] = x;
}

// =================== launch ===================
extern "C" void kernel_launch(void* const* d_in, const int* in_sizes, int n_in,
                              void* d_out, int out_size, void* d_ws, size_t ws_size,
                              hipStream_t stream)
{
  const float* tgt      = (const float*)d_in[0];
  const float* memory   = (const float*)d_in[1];
  const float* tvec     = (const float*)d_in[2];
  const float* qk_w     = (const float*)d_in[3];
  const float* v_w      = (const float*)d_in[4];
  const float* ds_lw    = (const float*)d_in[5];
  const float* ds_lb    = (const float*)d_in[6];
  const float* ta_in_w  = (const float*)d_in[7];
  const float* ta_in_b  = (const float*)d_in[8];
  const float* ta_out_w = (const float*)d_in[9];
  const float* ta_out_b = (const float*)d_in[10];
  const float* ca_in_w  = (const float*)d_in[11];
  const float* ca_in_b  = (const float*)d_in[12];
  const float* ca_out_w = (const float*)d_in[13];
  const float* ca_out_b = (const float*)d_in[14];
  const float* l1_w     = (const float*)d_in[15];
  const float* l1_b     = (const float*)d_in[16];
  const float* l2_w     = (const float*)d_in[17];
  const float* l2_b     = (const float*)d_in[18];
  const float* n1_g = (const float*)d_in[19]; const float* n1_b = (const float*)d_in[20];
  const float* n2_g = (const float*)d_in[21]; const float* n2_b = (const float*)d_in[22];
  const float* n3_g = (const float*)d_in[23]; const float* n3_b = (const float*)d_in[24];
  const float* n4_g = (const float*)d_in[25]; const float* n4_b = (const float*)d_in[26];
  const float* a1_w = (const float*)d_in[27]; const float* a1_b = (const float*)d_in[28];
  const float* a2_w = (const float*)d_in[29]; const float* a2_b = (const float*)d_in[30];
  const float* a3_w = (const float*)d_in[31]; const float* a3_b = (const float*)d_in[32];

  // ---- fixed workspace (bytes): bf16 weight copies ----
  const size_t W_QKT = 1280ULL * 512 * 2;
  const size_t W_VT  = 640ULL  * 512 * 2;
  const size_t W_TAI = 1536ULL * 512 * 2;
  const size_t W_TAO = 512ULL  * 512 * 2;
  const size_t W_CAI = 1536ULL * 512 * 2;
  const size_t W_CAO = 512ULL  * 512 * 2;
  const size_t W_L1  = 2048ULL * 512 * 2;
  const size_t W_L2  = 512ULL  * 2048 * 2;
  const size_t W_DSL = 512ULL  * 640 * 2;
  const size_t W_AX  = 1024ULL * 512 * 2;    // x3
  const size_t W_MEM = (size_t)BB * NN * 512 * 2;
  const size_t fixedB = W_QKT + W_VT + W_TAI + W_TAO + W_CAI + W_CAO
                      + W_L1 + W_L2 + W_DSL + 3 * W_AX + W_MEM;
  // per-batch: XNh bf16[300][512] + SCRB 300x4992B (COMB f32 1248 / QKV bf16 1536
  // / FFN bf16 2048) + Vdsh bf16[300][640] + Yb f32[300][512] + MMh bf16[512] + Hb f32[1024]
  const size_t per_b = 300ULL * (1024 + 4992 + 1280 + 2048) + 1024 + 4096;  // 2,808,320
  int Bc = 128;
  while (Bc > 16 && fixedB + (size_t)Bc * per_b > ws_size) Bc >>= 1;
  const int rows = Bc * NN;
  const int mB   = (rows + 127) / 128;
  const int aB   = (Bc + 127) / 128;
  const int nchunks = BB / Bc;

  char* p = (char*)d_ws;
  unsigned short* qkTh  = (unsigned short*)p; p += W_QKT;
  unsigned short* vTh   = (unsigned short*)p; p += W_VT;
  unsigned short* taiWh = (unsigned short*)p; p += W_TAI;
  unsigned short* taoWh = (unsigned short*)p; p += W_TAO;
  unsigned short* caiWh = (unsigned short*)p; p += W_CAI;
  unsigned short* caoWh = (unsigned short*)p; p += W_CAO;
  unsigned short* l1Wh  = (unsigned short*)p; p += W_L1;
  unsigned short* l2Wh  = (unsigned short*)p; p += W_L2;
  unsigned short* dslWh = (unsigned short*)p; p += W_DSL;
  unsigned short* a1Wh  = (unsigned short*)p; p += W_AX;
  unsigned short* a2Wh  = (unsigned short*)p; p += W_AX;
  unsigned short* a3Wh  = (unsigned short*)p; p += W_AX;
  unsigned short* memh  = (unsigned short*)p; p += W_MEM;
  unsigned short* XNh   = (unsigned short*)p; p += (size_t)rows * 512 * 2;
  char* SCRB = p;                             p += (size_t)rows * 4992;
  unsigned short* Vdsh  = (unsigned short*)p; p += (size_t)rows * 640 * 2;
  float* Yb  = (float*)p; p += (size_t)rows * 512 * 4;
  unsigned short* MMh = (unsigned short*)p;   p += (size_t)Bc * 512 * 2;
  float* Hb  = (float*)p;

  float* COMB = (float*)SCRB;                  // [rows][1248] f32
  unsigned short* QKVh = (unsigned short*)SCRB;// [rows][1536] bf16
  unsigned short* T2h  = (unsigned short*)SCRB;// [rows][2048] bf16

  dim3 thr(256);

  // ---- one-time weight / memory conversion ----
  transpose_bf16<<<dim3(40, 16), thr, 0, stream>>>(qk_w, qkTh, 512, 1248, 1280);
  transpose_bf16<<<dim3(20, 16), thr, 0, stream>>>(v_w,  vTh,  512, 624, 640);
  cvt_pad_bf16<<<dim3(512 * 640 / 256), thr, 0, stream>>>(ds_lw, dslWh, 512, 624, 640);
  auto cvt = [&](const float* src, unsigned short* dst, size_t n) {
    int n4 = (int)(n / 4);
    cvt_bf16<<<dim3((n4 + 255) / 256), thr, 0, stream>>>(src, dst, n4);
  };
  cvt(ta_in_w,  taiWh, 1536ULL * 512);
  cvt(ta_out_w, taoWh, 512ULL * 512);
  cvt(ca_in_w,  caiWh, 1536ULL * 512);
  cvt(ca_out_w, caoWh, 512ULL * 512);
  cvt(l1_w,     l1Wh,  2048ULL * 512);
  cvt(l2_w,     l2Wh,  512ULL * 2048);
  cvt(a1_w,     a1Wh,  1024ULL * 512);
  cvt(a2_w,     a2Wh,  1024ULL * 512);
  cvt(a3_w,     a3Wh,  1024ULL * 512);
  cvt(memory,   memh,  (size_t)BB * NN * 512);

  for (int c = 0; c < nchunks; ++c) {
    const size_t roff = (size_t)c * Bc * NN * DM;
    const float* tgtC = tgt    + roff;
    const float* tC   = tvec   + (size_t)c * Bc * 512;
    const unsigned short* memhC = memh + roff;
    float*       XC   = (float*)d_out + roff;

    // ---- ds-attention branch: x = tgt + ds_attn(LN1(tgt)) ----
    ln_kernel<<<rows / 4, thr, 0, stream>>>(tgtC, n1_g, n1_b, XNh, rows);
    gemm_bb<0><<<dim3(10, mB), thr, 0, stream>>>(XNh, 512, qkTh, 512, nullptr, nullptr, 0, COMB, 1248, rows, 512, 1248);
    gemm_bb<6><<<dim3(5, mB),  thr, 0, stream>>>(XNh, 512, vTh,  512, nullptr, nullptr, 0, Vdsh, 640,  rows, 512, 640);
    ds_attn_kernel<<<rows / 2, thr, 0, stream>>>(COMB, Vdsh);
    gemm_bb<3><<<dim3(4, mB),  thr, 0, stream>>>(Vdsh, 640, dslWh, 640, ds_lb, tgtC, 512, XC, 512, rows, 640, 512);

    // ---- self attention + align1 (+fused LN3) ----
    ln_kernel<<<rows / 4, thr, 0, stream>>>(XC, n2_g, n2_b, XNh, rows);
    gemm_bb<5><<<dim3(12, mB), thr, 0, stream>>>(XNh, 512, taiWh, 512, ta_in_b, nullptr, 0, QKVh, 1536, rows, 512, 1536);
    mha_mfma<<<Bc * 8, 512, 0, stream>>>(QKVh, 1536, 0, QKVh, 1536, 512, 1024, XNh, 0.125f);
    gemm_bb<1><<<dim3(4, mB),  thr, 0, stream>>>(XNh, 512, taoWh, 512, ta_out_b, nullptr, 0, Yb, 512, rows, 512, 512);
    colmean_mish<<<Bc * 2, thr, 0, stream>>>(Yb, tC, MMh);
    gemm_bb<1><<<dim3(8, aB),  thr, 0, stream>>>(MMh, 512, a1Wh, 512, a1_b, nullptr, 0, Hb, 1024, Bc, 512, 1024);
    align_ln<<<rows / 4, thr, 0, stream>>>(XC, Yb, Hb, n3_g, n3_b, XNh);

    // ---- cross attention + align2 (+fused LN4) ----
    gemm_bb<5><<<dim3(4, mB),  thr, 0, stream>>>(XNh, 512, caiWh, 512, ca_in_b, nullptr, 0, QKVh, 1536, rows, 512, 512);
    gemm_bb<5><<<dim3(8, mB),  thr, 0, stream>>>(memhC, 512, caiWh + 512 * 512, 512, ca_in_b + 512, nullptr, 0, QKVh + 512, 1536, rows, 512, 1024);
    mha_mfma<<<Bc * 8, 512, 0, stream>>>(QKVh, 1536, 0, QKVh, 1536, 512, 1024, XNh, 0.125f);
    gemm_bb<1><<<dim3(4, mB),  thr, 0, stream>>>(XNh, 512, caoWh, 512, ca_out_b, nullptr, 0, Yb, 512, rows, 512, 512);
    colmean_mish<<<Bc * 2, thr, 0, stream>>>(Yb, tC, MMh);
    gemm_bb<1><<<dim3(8, aB),  thr, 0, stream>>>(MMh, 512, a2Wh, 512, a2_b, nullptr, 0, Hb, 1024, Bc, 512, 1024);
    align_ln<<<rows / 4, thr, 0, stream>>>(XC, Yb, Hb, n4_g, n4_b, XNh);

    // ---- FFN (merged N=2048, K=2048) + align3 ----
    gemm_bb<2><<<dim3(16, mB), thr, 0, stream>>>(XNh, 512, l1Wh, 512, l1_b, nullptr, 0, T2h, 2048, rows, 512, 2048);
    gemm_bb<1><<<dim3(4, mB),  thr, 0, stream>>>(T2h, 2048, l2Wh, 2048, l2_b, nullptr, 0, Yb, 512, rows, 2048, 512);
    colmean_mish<<<Bc * 2, thr, 0, stream>>>(Yb, tC, MMh);
    gemm_bb<1><<<dim3(8, aB),  thr, 0, stream>>>(MMh, 512, a3Wh, 512, a3_b, nullptr, 0, Hb, 1024, Bc, 512, 1024);
    align_apply<<<rows / 2, thr, 0, stream>>>(XC, Yb, Hb);
  }
}